// Round 3
// baseline (960.885 us; speedup 1.0000x reference)
//
#include <hip/hip_runtime.h>

#define N_NODES 100000
#define N_EDGES 3200000
#define F_INN 512
#define HIDD 16
#define NGR 256
#define NBN 391            // ceil(N_NODES/256)
#define BSH 6              // bucket = dst >> 6 (64 nodes per bucket)
#define NBUK 1563          // ceil(N_NODES/64)

// ---------------- in-degree count (int atomics, L2-resident) ----------------
__global__ __launch_bounds__(256) void k_deg(const int* __restrict__ ei, int* __restrict__ cnt) {
  int e = blockIdx.x * 256 + threadIdx.x;
  if (e < N_EDGES) atomicAdd(&cnt[ei[N_EDGES + e]], 1);
}

// ---------------- per-block exclusive scan of cnt + dinv ----------------
__global__ __launch_bounds__(256) void k_scan1(const int* __restrict__ cnt,
                                               int* __restrict__ offs,
                                               int* __restrict__ bsum,
                                               float* __restrict__ dinv) {
  __shared__ int s[256];
  int t = threadIdx.x;
  int i = blockIdx.x * 256 + t;
  int v = (i < N_NODES) ? cnt[i] : 0;
  s[t] = v;
  __syncthreads();
  for (int o = 1; o < 256; o <<= 1) {
    int add = (t >= o) ? s[t - o] : 0;
    __syncthreads();
    s[t] += add;
    __syncthreads();
  }
  if (i < N_NODES) {
    offs[i] = s[t] - v;                    // block-local exclusive
    dinv[i] = rsqrtf((float)v + 1.0f);     // +1 self loop
  }
  if (t == 255) bsum[blockIdx.x] = s[255];
}

// serial scan of 391 block sums
__global__ void k_scan2(int* __restrict__ bsum) {
  if (threadIdx.x == 0 && blockIdx.x == 0) {
    int acc = 0;
    for (int i = 0; i < NBN; ++i) { int v = bsum[i]; bsum[i] = acc; acc += v; }
  }
}

__device__ __forceinline__ int node_start(const int* offs, const int* bsum, int n) {
  return offs[n] + bsum[n >> 8];
}

// ---------------- bucket append: buck[pos] = (src<<6)|(dst&63), bucketed by dst>>6 ----------------
__global__ __launch_bounds__(256) void k_bucket(const int* __restrict__ ei,
                                                const int* __restrict__ offs,
                                                const int* __restrict__ bsum,
                                                int* __restrict__ bcursor,
                                                int* __restrict__ buck) {
  int e = blockIdx.x * 256 + threadIdx.x;
  if (e < N_EDGES) {
    int s = ei[e];
    int d = ei[N_EDGES + e];
    int b = d >> BSH;
    int bst = node_start(offs, bsum, d & ~63);
    int pos = bst + atomicAdd(&bcursor[b], 1);
    buck[pos] = (s << BSH) | (d & 63);
  }
}

// ---------------- per-bucket CSR fill (all writes within an ~8KB L2-resident span) ----------------
__global__ __launch_bounds__(256) void k_fill2(const int* __restrict__ buck,
                                               const int* __restrict__ offs,
                                               const int* __restrict__ bsum,
                                               int* __restrict__ cursor,
                                               int* __restrict__ csr) {
  int b = blockIdx.x;
  int n0 = b << BSH;
  int n1 = (b + 1) << BSH;
  int start = node_start(offs, bsum, n0);
  int end = (n1 < N_NODES) ? node_start(offs, bsum, n1) : N_EDGES;
  for (int i = start + threadIdx.x; i < end; i += 256) {
    int v = buck[i];
    int d = n0 + (v & 63);
    int pos = node_start(offs, bsum, d) + atomicAdd(&cursor[d], 1);
    csr[pos] = v >> BSH;
  }
}

// ---------------- GEMM1: t1 = X @ W1 ----------------
__global__ __launch_bounds__(128) void k_gemm1(const float* __restrict__ X,
                                               const float* __restrict__ W,
                                               float* __restrict__ T1) {
  __shared__ float Ws[64 * 16];        // 4 KB
  __shared__ float Xs[2][64 * 65];     // 33.3 KB
  const int wave = threadIdx.x >> 6;
  const int lane = threadIdx.x & 63;
  const int rowBase = blockIdx.x * 128 + wave * 64;
  const int myRow = rowBase + lane;

  float acc[16];
#pragma unroll
  for (int j = 0; j < 16; ++j) acc[j] = 0.f;

  for (int kt = 0; kt < F_INN; kt += 64) {
    {
      int t = threadIdx.x;
      float4 w0 = *(const float4*)(W + kt * 16 + t * 8);
      float4 w1 = *(const float4*)(W + kt * 16 + t * 8 + 4);
      *(float4*)(&Ws[t * 8]) = w0;
      *(float4*)(&Ws[t * 8 + 4]) = w1;
    }
#pragma unroll
    for (int i = 0; i < 16; ++i) {
      int f = i * 64 + lane;
      int r = f >> 4;
      int kq = f & 15;
      int gr = rowBase + r;
      float4 v = make_float4(0.f, 0.f, 0.f, 0.f);
      if (gr < N_NODES) v = *(const float4*)(X + (size_t)gr * F_INN + kt + kq * 4);
      float* p = &Xs[wave][r * 65 + kq * 4];
      p[0] = v.x; p[1] = v.y; p[2] = v.z; p[3] = v.w;
    }
    __syncthreads();
#pragma unroll 8
    for (int k = 0; k < 64; ++k) {
      float xv = Xs[wave][lane * 65 + k];
#pragma unroll
      for (int j = 0; j < 16; ++j) acc[j] = fmaf(xv, Ws[k * 16 + j], acc[j]);
    }
    __syncthreads();
  }

  if (myRow < N_NODES) {
    float4* t = (float4*)(T1 + (size_t)myRow * 16);
#pragma unroll
    for (int q = 0; q < 4; ++q)
      t[q] = make_float4(acc[q * 4 + 0], acc[q * 4 + 1], acc[q * 4 + 2], acc[q * 4 + 3]);
  }
}

// ---------------- gather layer 1 ----------------
__global__ __launch_bounds__(256) void k_gather1(const int* __restrict__ csr,
                                                 const int* __restrict__ offs,
                                                 const int* __restrict__ bsum,
                                                 const int* __restrict__ cnt,
                                                 const float* __restrict__ dinv,
                                                 const float* __restrict__ T1,
                                                 float* __restrict__ O1) {
  int node = blockIdx.x * 64 + (threadIdx.x >> 2);
  int q = threadIdx.x & 3;
  if (node >= N_NODES) return;
  float dd = dinv[node];
  int start = offs[node] + bsum[node >> 8];
  int len = cnt[node];
  float4 v = *(const float4*)(T1 + (size_t)node * 16 + q * 4);
  float w0 = dd * dd;
  float4 acc = make_float4(w0 * v.x, w0 * v.y, w0 * v.z, w0 * v.w);
  for (int i = 0; i < len; ++i) {
    int s = csr[start + i];
    float w = dinv[s] * dd;
    float4 u = *(const float4*)(T1 + (size_t)s * 16 + q * 4);
    acc.x = fmaf(w, u.x, acc.x);
    acc.y = fmaf(w, u.y, acc.y);
    acc.z = fmaf(w, u.z, acc.z);
    acc.w = fmaf(w, u.w, acc.w);
  }
  *(float4*)(O1 + (size_t)node * 16 + q * 4) = acc;
}

// ---------------- layer 2: h = relu(o1 + b1); t2 = h @ W2 ----------------
__global__ __launch_bounds__(256) void k_l2(const float* __restrict__ O1,
                                            const float* __restrict__ b1,
                                            const float* __restrict__ W2,
                                            float* __restrict__ T2) {
  int i = blockIdx.x * 256 + threadIdx.x;
  if (i >= N_NODES) return;
  const float4* r4 = (const float4*)(O1 + (size_t)i * 16);
  float a0 = 0.f, a1 = 0.f;
#pragma unroll
  for (int q = 0; q < 4; ++q) {
    float4 v = r4[q];
    float h0 = fmaxf(v.x + b1[q * 4 + 0], 0.f);
    float h1 = fmaxf(v.y + b1[q * 4 + 1], 0.f);
    float h2 = fmaxf(v.z + b1[q * 4 + 2], 0.f);
    float h3 = fmaxf(v.w + b1[q * 4 + 3], 0.f);
    a0 = fmaf(h0, W2[(q * 4 + 0) * 2], fmaf(h1, W2[(q * 4 + 1) * 2], fmaf(h2, W2[(q * 4 + 2) * 2], fmaf(h3, W2[(q * 4 + 3) * 2], a0))));
    a1 = fmaf(h0, W2[(q * 4 + 0) * 2 + 1], fmaf(h1, W2[(q * 4 + 1) * 2 + 1], fmaf(h2, W2[(q * 4 + 2) * 2 + 1], fmaf(h3, W2[(q * 4 + 3) * 2 + 1], a1))));
  }
  T2[i * 2 + 0] = a0;
  T2[i * 2 + 1] = a1;
}

// ---------------- gather layer 2 ----------------
__global__ __launch_bounds__(256) void k_gather2(const int* __restrict__ csr,
                                                 const int* __restrict__ offs,
                                                 const int* __restrict__ bsum,
                                                 const int* __restrict__ cnt,
                                                 const float* __restrict__ dinv,
                                                 const float* __restrict__ T2,
                                                 float* __restrict__ O2) {
  int node = blockIdx.x * 256 + threadIdx.x;
  if (node >= N_NODES) return;
  float dd = dinv[node];
  int start = offs[node] + bsum[node >> 8];
  int len = cnt[node];
  float2 v = *(const float2*)(T2 + (size_t)node * 2);
  float w0 = dd * dd;
  float ax = w0 * v.x, ay = w0 * v.y;
  for (int i = 0; i < len; ++i) {
    int s = csr[start + i];
    float w = dinv[s] * dd;
    float2 u = *(const float2*)(T2 + (size_t)s * 2);
    ax = fmaf(w, u.x, ax);
    ay = fmaf(w, u.y, ay);
  }
  O2[node * 2 + 0] = ax;
  O2[node * 2 + 1] = ay;
}

// ---------------- pooling ----------------
__global__ __launch_bounds__(256) void k_pool(const float* __restrict__ O2,
                                              const int* __restrict__ batch,
                                              float* __restrict__ pool,
                                              float* __restrict__ gcnt) {
  int i = blockIdx.x * 256 + threadIdx.x;
  bool valid = i < N_NODES;
  int b = valid ? batch[i] : -1;
  float vx = 0.f, vy = 0.f;
  if (valid) {
    vx = O2[(size_t)i * 2 + 0];
    vy = O2[(size_t)i * 2 + 1];
  }
  int b0 = __shfl(b, 0);
  if (__all(b == b0)) {
    if (b0 >= 0) {
#pragma unroll
      for (int o = 32; o > 0; o >>= 1) {
        vx += __shfl_xor(vx, o);
        vy += __shfl_xor(vy, o);
      }
      if ((threadIdx.x & 63) == 0) {
        atomicAdd(&pool[b0 * 2 + 0], vx);
        atomicAdd(&pool[b0 * 2 + 1], vy);
        atomicAdd(&gcnt[b0], 64.0f);
      }
    }
  } else if (valid) {
    atomicAdd(&pool[b * 2 + 0], vx);
    atomicAdd(&pool[b * 2 + 1], vy);
    atomicAdd(&gcnt[b], 1.0f);
  }
}

// ---------------- final ----------------
__global__ __launch_bounds__(256) void k_final(const float* __restrict__ pool,
                                               const float* __restrict__ gcnt,
                                               const float* __restrict__ b2,
                                               float* __restrict__ out) {
  int g = threadIdx.x;
  if (g < NGR) {
    float c = fmaxf(gcnt[g], 1.0f);
    float p0 = pool[g * 2 + 0] / c + b2[0];
    float p1 = pool[g * 2 + 1] / c + b2[1];
    float m = fmaxf(p0, p1);
    float l = logf(expf(p0 - m) + expf(p1 - m));
    out[g * 2 + 0] = p0 - m - l;
    out[g * 2 + 1] = p1 - m - l;
  }
}

extern "C" void kernel_launch(void* const* d_in, const int* in_sizes, int n_in,
                              void* d_out, int out_size, void* d_ws, size_t ws_size,
                              hipStream_t stream) {
  const float* x  = (const float*)d_in[0];
  const float* W1 = (const float*)d_in[1];
  const float* b1 = (const float*)d_in[2];
  const float* W2 = (const float*)d_in[3];
  const float* b2 = (const float*)d_in[4];
  const int*   ei = (const int*)d_in[5];
  const int*   bt = (const int*)d_in[6];
  float* out = (float*)d_out;

  char* ws = (char*)d_ws;
  int*   cnt     = (int*)ws;   ws += (size_t)N_NODES * 4;
  int*   cursor  = (int*)ws;   ws += (size_t)N_NODES * 4;
  int*   bcursor = (int*)ws;   ws += (size_t)((NBUK + 1) & ~1) * 4;
  float* dinv    = (float*)ws; ws += (size_t)N_NODES * 4;
  int*   offs    = (int*)ws;   ws += (size_t)N_NODES * 4;
  int*   bsum    = (int*)ws;   ws += 512 * 4;
  int*   csr     = (int*)ws;   ws += (size_t)N_EDGES * 4;
  // buck aliases the t1/o1 region (dead once k_fill2 completes, before k_gemm1)
  int*   buck    = (int*)ws;
  float* t1      = (float*)ws; ws += (size_t)N_NODES * 16 * 4;
  float* o1      = (float*)ws; ws += (size_t)N_NODES * 16 * 4;
  float* pool    = (float*)ws; ws += 2 * NGR * 4;
  float* gcnt    = (float*)ws; ws += NGR * 4;
  // t2/o2 alias t1 (dead after k_gather1)
  float* t2 = t1;
  float* o2 = t1 + (size_t)N_NODES * 2;

  // one memset covers cnt + cursor + bcursor (contiguous)
  hipMemsetAsync(cnt, 0, (size_t)(2 * N_NODES + ((NBUK + 1) & ~1)) * 4, stream);
  hipMemsetAsync(pool, 0, (size_t)(3 * NGR) * 4, stream);

  k_deg   <<<N_EDGES / 256, 256, 0, stream>>>(ei, cnt);
  k_scan1 <<<NBN, 256, 0, stream>>>(cnt, offs, bsum, dinv);
  k_scan2 <<<1, 64, 0, stream>>>(bsum);
  k_bucket<<<N_EDGES / 256, 256, 0, stream>>>(ei, offs, bsum, bcursor, buck);
  k_fill2 <<<NBUK, 256, 0, stream>>>(buck, offs, bsum, cursor, csr);
  k_gemm1 <<<(N_NODES + 127) / 128, 128, 0, stream>>>(x, W1, t1);
  k_gather1<<<(N_NODES + 63) / 64, 256, 0, stream>>>(csr, offs, bsum, cnt, dinv, t1, o1);
  k_l2    <<<NBN, 256, 0, stream>>>(o1, b1, W2, t2);
  k_gather2<<<NBN, 256, 0, stream>>>(csr, offs, bsum, cnt, dinv, t2, o2);
  k_pool  <<<NBN, 256, 0, stream>>>(o2, bt, pool, gcnt);
  k_final <<<1, 256, 0, stream>>>(pool, gcnt, b2, out);
}

// Round 4
// 593.357 us; speedup vs baseline: 1.6194x; 1.6194x over previous
//
#include <hip/hip_runtime.h>

#define N_NODES 100000
#define N_EDGES 3200000
#define F_INN 512
#define NGR 256
#define NB 391             // bins of 256 nodes: bin = dst >> 8
#define KBB 256            // binning blocks
#define CHUNK (N_EDGES / KBB)   // 12500 exactly
#define APAD 17            // LDS accumulator row stride (pad vs 16)

// ---------------- per-bin totals via LDS histograms ----------------
__global__ __launch_bounds__(256) void k_binhist(const int* __restrict__ ei,
                                                 int* __restrict__ bintot) {
  __shared__ int h[NB];
  for (int t = threadIdx.x; t < NB; t += 256) h[t] = 0;
  __syncthreads();
  int e0 = blockIdx.x * CHUNK;
  for (int i = threadIdx.x; i < CHUNK; i += 256)
    atomicAdd(&h[ei[N_EDGES + e0 + i] >> 8], 1);
  __syncthreads();
  for (int t = threadIdx.x; t < NB; t += 256)
    if (h[t]) atomicAdd(&bintot[t], h[t]);
}

// ---------------- exclusive scan of 391 bin totals (one block) ----------------
__global__ __launch_bounds__(512) void k_scanbins(const int* __restrict__ bintot,
                                                  int* __restrict__ bsum) {
  __shared__ int s[512];
  int t = threadIdx.x;
  int v = (t < NB) ? bintot[t] : 0;
  s[t] = v;
  __syncthreads();
  for (int o = 1; o < 512; o <<= 1) {
    int add = (t >= o) ? s[t - o] : 0;
    __syncthreads();
    s[t] += add;
    __syncthreads();
  }
  if (t <= NB) bsum[t] = s[t] - v;   // t==NB: v==0 -> total = N_EDGES
}

// ---------------- binning: rec[bin segment] = (src<<8)|(dst&255) ----------------
// Per block: LDS histogram -> one global cursor reservation per bin -> write
// block-private contiguous segments (lines fill completely).
__global__ __launch_bounds__(256) void k_bin(const int* __restrict__ ei,
                                             const int* __restrict__ bsum,
                                             int* __restrict__ bincur,
                                             int* __restrict__ rec) {
  __shared__ int h[NB];
  __shared__ int base[NB];
  for (int t = threadIdx.x; t < NB; t += 256) h[t] = 0;
  __syncthreads();
  int e0 = blockIdx.x * CHUNK;
  for (int i = threadIdx.x; i < CHUNK; i += 256)
    atomicAdd(&h[ei[N_EDGES + e0 + i] >> 8], 1);
  __syncthreads();
  for (int t = threadIdx.x; t < NB; t += 256) {
    int c = h[t];
    base[t] = bsum[t] + (c ? atomicAdd(&bincur[t], c) : 0);
    h[t] = 0;                       // reuse as local cursor
  }
  __syncthreads();
  for (int i = threadIdx.x; i < CHUNK; i += 256) {
    int s = ei[e0 + i];
    int d = ei[N_EDGES + e0 + i];
    int k = d >> 8;
    int pos = base[k] + atomicAdd(&h[k], 1);
    rec[pos] = (s << 8) | (d & 255);
  }
}

// ---------------- per-node degree (from records, LDS only) -> dinv ----------------
__global__ __launch_bounds__(256) void k_dinv(const int* __restrict__ rec,
                                              const int* __restrict__ bsum,
                                              float* __restrict__ dinv) {
  __shared__ int h[256];
  int k = blockIdx.x;
  h[threadIdx.x] = 0;
  __syncthreads();
  int start = bsum[k], end = bsum[k + 1];
  for (int r = start + threadIdx.x; r < end; r += 256)
    atomicAdd(&h[rec[r] & 255], 1);
  __syncthreads();
  int node = (k << 8) + threadIdx.x;
  if (node < N_NODES) dinv[node] = rsqrtf((float)h[threadIdx.x] + 1.0f);
}

// ---------------- GEMM1: t1 = X @ W1 ----------------
__global__ __launch_bounds__(128) void k_gemm1(const float* __restrict__ X,
                                               const float* __restrict__ W,
                                               float* __restrict__ T1) {
  __shared__ float Ws[64 * 16];
  __shared__ float Xs[2][64 * 65];
  const int wave = threadIdx.x >> 6;
  const int lane = threadIdx.x & 63;
  const int rowBase = blockIdx.x * 128 + wave * 64;
  const int myRow = rowBase + lane;

  float acc[16];
#pragma unroll
  for (int j = 0; j < 16; ++j) acc[j] = 0.f;

  for (int kt = 0; kt < F_INN; kt += 64) {
    {
      int t = threadIdx.x;
      float4 w0 = *(const float4*)(W + kt * 16 + t * 8);
      float4 w1 = *(const float4*)(W + kt * 16 + t * 8 + 4);
      *(float4*)(&Ws[t * 8]) = w0;
      *(float4*)(&Ws[t * 8 + 4]) = w1;
    }
#pragma unroll
    for (int i = 0; i < 16; ++i) {
      int f = i * 64 + lane;
      int r = f >> 4;
      int kq = f & 15;
      int gr = rowBase + r;
      float4 v = make_float4(0.f, 0.f, 0.f, 0.f);
      if (gr < N_NODES) v = *(const float4*)(X + (size_t)gr * F_INN + kt + kq * 4);
      float* p = &Xs[wave][r * 65 + kq * 4];
      p[0] = v.x; p[1] = v.y; p[2] = v.z; p[3] = v.w;
    }
    __syncthreads();
#pragma unroll 8
    for (int k = 0; k < 64; ++k) {
      float xv = Xs[wave][lane * 65 + k];
#pragma unroll
      for (int j = 0; j < 16; ++j) acc[j] = fmaf(xv, Ws[k * 16 + j], acc[j]);
    }
    __syncthreads();
  }

  if (myRow < N_NODES) {
    float4* t = (float4*)(T1 + (size_t)myRow * 16);
#pragma unroll
    for (int q = 0; q < 4; ++q)
      t[q] = make_float4(acc[q * 4 + 0], acc[q * 4 + 1], acc[q * 4 + 2], acc[q * 4 + 3]);
  }
}

// ---------------- layer-1 aggregation + bias/ReLU/W2 fused -> t2 ----------------
// One block per bin; LDS accumulator owns the 256-node range exclusively.
__global__ __launch_bounds__(256) void k_agg1(const int* __restrict__ rec,
                                              const int* __restrict__ bsum,
                                              const float* __restrict__ dinv,
                                              const float* __restrict__ T1,
                                              const float* __restrict__ b1,
                                              const float* __restrict__ W2,
                                              float* __restrict__ T2) {
  __shared__ float acc[256 * APAD];
  int k = blockIdx.x;
  int n0 = k << 8;
  int nmax = min(256, N_NODES - n0);
  for (int idx = threadIdx.x; idx < nmax * 16; idx += 256) {
    int n = idx >> 4, c = idx & 15;
    float d = dinv[n0 + n];
    acc[n * APAD + c] = d * d * T1[(size_t)(n0 + n) * 16 + c];   // self loop
  }
  __syncthreads();
  int start = bsum[k], end = bsum[k + 1];
  int q = threadIdx.x & 3;
  for (int r = start + (threadIdx.x >> 2); r < end; r += 64) {
    int v = rec[r];
    int s = v >> 8;
    int dl = v & 255;
    float w = dinv[s] * dinv[n0 + dl];
    float4 u = *(const float4*)(T1 + (size_t)s * 16 + q * 4);
    float* a = &acc[dl * APAD + q * 4];
    atomicAdd(a + 0, w * u.x);
    atomicAdd(a + 1, w * u.y);
    atomicAdd(a + 2, w * u.z);
    atomicAdd(a + 3, w * u.w);
  }
  __syncthreads();
  int t = threadIdx.x;
  if (t < nmax) {
    float a0 = 0.f, a1 = 0.f;
#pragma unroll
    for (int c = 0; c < 16; ++c) {
      float hv = fmaxf(acc[t * APAD + c] + b1[c], 0.f);
      a0 = fmaf(hv, W2[c * 2 + 0], a0);
      a1 = fmaf(hv, W2[c * 2 + 1], a1);
    }
    T2[(size_t)(n0 + t) * 2 + 0] = a0;
    T2[(size_t)(n0 + t) * 2 + 1] = a1;
  }
}

// ---------------- layer-2 aggregation -> o2 ----------------
__global__ __launch_bounds__(256) void k_agg2(const int* __restrict__ rec,
                                              const int* __restrict__ bsum,
                                              const float* __restrict__ dinv,
                                              const float* __restrict__ T2,
                                              float* __restrict__ O2) {
  __shared__ float acc[256 * 3];
  int k = blockIdx.x;
  int n0 = k << 8;
  int nmax = min(256, N_NODES - n0);
  int t = threadIdx.x;
  if (t < nmax) {
    float d = dinv[n0 + t];
    acc[t * 3 + 0] = d * d * T2[(size_t)(n0 + t) * 2 + 0];
    acc[t * 3 + 1] = d * d * T2[(size_t)(n0 + t) * 2 + 1];
  }
  __syncthreads();
  int start = bsum[k], end = bsum[k + 1];
  int c = t & 1;
  for (int r = start + (t >> 1); r < end; r += 128) {
    int v = rec[r];
    int s = v >> 8;
    int dl = v & 255;
    float w = dinv[s] * dinv[n0 + dl];
    atomicAdd(&acc[dl * 3 + c], w * T2[(size_t)s * 2 + c]);
  }
  __syncthreads();
  if (t < nmax) {
    O2[(size_t)(n0 + t) * 2 + 0] = acc[t * 3 + 0];
    O2[(size_t)(n0 + t) * 2 + 1] = acc[t * 3 + 1];
  }
}

// ---------------- pooling (batch sorted -> wave fast path) ----------------
__global__ __launch_bounds__(256) void k_pool(const float* __restrict__ O2,
                                              const int* __restrict__ batch,
                                              float* __restrict__ pool,
                                              float* __restrict__ gcnt) {
  int i = blockIdx.x * 256 + threadIdx.x;
  bool valid = i < N_NODES;
  int b = valid ? batch[i] : -1;
  float vx = 0.f, vy = 0.f;
  if (valid) {
    vx = O2[(size_t)i * 2 + 0];
    vy = O2[(size_t)i * 2 + 1];
  }
  int b0 = __shfl(b, 0);
  if (__all(b == b0)) {
    if (b0 >= 0) {
#pragma unroll
      for (int o = 32; o > 0; o >>= 1) {
        vx += __shfl_xor(vx, o);
        vy += __shfl_xor(vy, o);
      }
      if ((threadIdx.x & 63) == 0) {
        atomicAdd(&pool[b0 * 2 + 0], vx);
        atomicAdd(&pool[b0 * 2 + 1], vy);
        atomicAdd(&gcnt[b0], 64.0f);
      }
    }
  } else if (valid) {
    atomicAdd(&pool[b * 2 + 0], vx);
    atomicAdd(&pool[b * 2 + 1], vy);
    atomicAdd(&gcnt[b], 1.0f);
  }
}

// ---------------- final ----------------
__global__ __launch_bounds__(256) void k_final(const float* __restrict__ pool,
                                               const float* __restrict__ gcnt,
                                               const float* __restrict__ b2,
                                               float* __restrict__ out) {
  int g = threadIdx.x;
  if (g < NGR) {
    float c = fmaxf(gcnt[g], 1.0f);
    float p0 = pool[g * 2 + 0] / c + b2[0];
    float p1 = pool[g * 2 + 1] / c + b2[1];
    float m = fmaxf(p0, p1);
    float l = logf(expf(p0 - m) + expf(p1 - m));
    out[g * 2 + 0] = p0 - m - l;
    out[g * 2 + 1] = p1 - m - l;
  }
}

extern "C" void kernel_launch(void* const* d_in, const int* in_sizes, int n_in,
                              void* d_out, int out_size, void* d_ws, size_t ws_size,
                              hipStream_t stream) {
  const float* x  = (const float*)d_in[0];
  const float* W1 = (const float*)d_in[1];
  const float* b1 = (const float*)d_in[2];
  const float* W2 = (const float*)d_in[3];
  const float* b2 = (const float*)d_in[4];
  const int*   ei = (const int*)d_in[5];
  const int*   bt = (const int*)d_in[6];
  float* out = (float*)d_out;

  char* ws = (char*)d_ws;
  int*   bintot = (int*)ws;    ws += 392 * 4;
  int*   bincur = (int*)ws;    ws += 392 * 4;
  float* pool   = (float*)ws;  ws += 2 * NGR * 4;
  float* gcnt   = (float*)ws;  ws += NGR * 4;     // [bintot..gcnt] one memset
  int*   bsum   = (int*)ws;    ws += 392 * 4;
  float* dinv   = (float*)ws;  ws += (size_t)N_NODES * 4;
  int*   rec    = (int*)ws;    ws += (size_t)N_EDGES * 4;
  float* t1     = (float*)ws;  ws += (size_t)N_NODES * 16 * 4;
  float* t2     = (float*)ws;  ws += (size_t)N_NODES * 2 * 4;
  float* o2     = (float*)ws;  ws += (size_t)N_NODES * 2 * 4;

  hipMemsetAsync(bintot, 0, (392 + 392 + 2 * NGR + NGR) * 4, stream);

  k_binhist <<<KBB, 256, 0, stream>>>(ei, bintot);
  k_scanbins<<<1, 512, 0, stream>>>(bintot, bsum);
  k_bin     <<<KBB, 256, 0, stream>>>(ei, bsum, bincur, rec);
  k_dinv    <<<NB, 256, 0, stream>>>(rec, bsum, dinv);
  k_gemm1   <<<(N_NODES + 127) / 128, 128, 0, stream>>>(x, W1, t1);
  k_agg1    <<<NB, 256, 0, stream>>>(rec, bsum, dinv, t1, b1, W2, t2);
  k_agg2    <<<NB, 256, 0, stream>>>(rec, bsum, dinv, t2, o2);
  k_pool    <<<NB, 256, 0, stream>>>(o2, bt, pool, gcnt);
  k_final   <<<1, 256, 0, stream>>>(pool, gcnt, b2, out);
}

// Round 5
// 524.720 us; speedup vs baseline: 1.8312x; 1.1308x over previous
//
#include <hip/hip_runtime.h>

#define N_NODES 100000
#define N_EDGES 3200000
#define F_INN 512
#define NGR 256
#define BSH 6                    // bin = dst >> 6 (64 nodes per bin)
#define NBIN 1563                // ceil(N_NODES/64)
#define KBB 256                  // binning blocks
#define CHUNK (N_EDGES / KBB)    // 12500 exactly
#define APAD 17                  // LDS accumulator row stride

// ---------------- per-bin totals via LDS histograms ----------------
__global__ __launch_bounds__(256) void k_binhist(const int* __restrict__ ei,
                                                 int* __restrict__ bintot) {
  __shared__ int h[NBIN];
  for (int t = threadIdx.x; t < NBIN; t += 256) h[t] = 0;
  __syncthreads();
  int e0 = blockIdx.x * CHUNK;
  for (int i = threadIdx.x; i < CHUNK; i += 256)
    atomicAdd(&h[ei[N_EDGES + e0 + i] >> BSH], 1);
  __syncthreads();
  for (int t = threadIdx.x; t < NBIN; t += 256)
    if (h[t]) atomicAdd(&bintot[t], h[t]);
}

// ---------------- exclusive scan of NBIN bin totals (one block, 2 elems/thread) ----------------
__global__ __launch_bounds__(1024) void k_scanbins(const int* __restrict__ bintot,
                                                   int* __restrict__ bsum) {
  __shared__ int s[1024];
  int t = threadIdx.x;
  int i0 = 2 * t, i1 = 2 * t + 1;
  int a = (i0 < NBIN) ? bintot[i0] : 0;
  int b = (i1 < NBIN) ? bintot[i1] : 0;
  s[t] = a + b;
  __syncthreads();
  for (int o = 1; o < 1024; o <<= 1) {
    int add = (t >= o) ? s[t - o] : 0;
    __syncthreads();
    s[t] += add;
    __syncthreads();
  }
  int excl = t ? s[t - 1] : 0;
  if (i0 <= NBIN) bsum[i0] = excl;
  if (i1 <= NBIN) bsum[i1] = excl + a;
}

// ---------------- binning: rec[bin segment] = (src<<6)|(dst&63) ----------------
__global__ __launch_bounds__(256) void k_bin(const int* __restrict__ ei,
                                             const int* __restrict__ bsum,
                                             int* __restrict__ bincur,
                                             int* __restrict__ rec) {
  __shared__ int h[NBIN];
  __shared__ int base[NBIN];
  for (int t = threadIdx.x; t < NBIN; t += 256) h[t] = 0;
  __syncthreads();
  int e0 = blockIdx.x * CHUNK;
  for (int i = threadIdx.x; i < CHUNK; i += 256)
    atomicAdd(&h[ei[N_EDGES + e0 + i] >> BSH], 1);
  __syncthreads();
  for (int t = threadIdx.x; t < NBIN; t += 256) {
    int c = h[t];
    base[t] = bsum[t] + (c ? atomicAdd(&bincur[t], c) : 0);
    h[t] = 0;                       // reuse as local cursor
  }
  __syncthreads();
  for (int i = threadIdx.x; i < CHUNK; i += 256) {
    int s = ei[e0 + i];
    int d = ei[N_EDGES + e0 + i];
    int k = d >> BSH;
    int pos = base[k] + atomicAdd(&h[k], 1);
    rec[pos] = (s << BSH) | (d & 63);
  }
}

// ---------------- per-node degree (from records) -> dinv ----------------
__global__ __launch_bounds__(256) void k_dinv(const int* __restrict__ rec,
                                              const int* __restrict__ bsum,
                                              float* __restrict__ dinv) {
  __shared__ int h[64];
  int k = blockIdx.x;
  if (threadIdx.x < 64) h[threadIdx.x] = 0;
  __syncthreads();
  int start = bsum[k], end = bsum[k + 1];
  for (int r = start + threadIdx.x; r < end; r += 256)
    atomicAdd(&h[rec[r] & 63], 1);
  __syncthreads();
  int node = (k << BSH) + threadIdx.x;
  if (threadIdx.x < 64 && node < N_NODES)
    dinv[node] = rsqrtf((float)h[threadIdx.x] + 1.0f);
}

// ---------------- GEMM1: t1' = dinv * (X @ W1) ----------------
__global__ __launch_bounds__(128) void k_gemm1(const float* __restrict__ X,
                                               const float* __restrict__ W,
                                               const float* __restrict__ dinv,
                                               float* __restrict__ T1) {
  __shared__ float Ws[64 * 16];
  __shared__ float Xs[2][64 * 65];
  const int wave = threadIdx.x >> 6;
  const int lane = threadIdx.x & 63;
  const int rowBase = blockIdx.x * 128 + wave * 64;
  const int myRow = rowBase + lane;

  float acc[16];
#pragma unroll
  for (int j = 0; j < 16; ++j) acc[j] = 0.f;

  for (int kt = 0; kt < F_INN; kt += 64) {
    {
      int t = threadIdx.x;
      float4 w0 = *(const float4*)(W + kt * 16 + t * 8);
      float4 w1 = *(const float4*)(W + kt * 16 + t * 8 + 4);
      *(float4*)(&Ws[t * 8]) = w0;
      *(float4*)(&Ws[t * 8 + 4]) = w1;
    }
#pragma unroll
    for (int i = 0; i < 16; ++i) {
      int f = i * 64 + lane;
      int r = f >> 4;
      int kq = f & 15;
      int gr = rowBase + r;
      float4 v = make_float4(0.f, 0.f, 0.f, 0.f);
      if (gr < N_NODES) v = *(const float4*)(X + (size_t)gr * F_INN + kt + kq * 4);
      float* p = &Xs[wave][r * 65 + kq * 4];
      p[0] = v.x; p[1] = v.y; p[2] = v.z; p[3] = v.w;
    }
    __syncthreads();
#pragma unroll 8
    for (int k = 0; k < 64; ++k) {
      float xv = Xs[wave][lane * 65 + k];
#pragma unroll
      for (int j = 0; j < 16; ++j) acc[j] = fmaf(xv, Ws[k * 16 + j], acc[j]);
    }
    __syncthreads();
  }

  if (myRow < N_NODES) {
    float di = dinv[myRow];
    float4* t = (float4*)(T1 + (size_t)myRow * 16);
#pragma unroll
    for (int q = 0; q < 4; ++q)
      t[q] = make_float4(di * acc[q * 4 + 0], di * acc[q * 4 + 1],
                         di * acc[q * 4 + 2], di * acc[q * 4 + 3]);
  }
}

// ---------------- layer-1 aggregation + bias/ReLU/W2 fused -> t2' = dinv*t2 ----------------
// o1[d] = dinv[d] * (t1'[d] + sum t1'[src]); hot loop = rec load + gather + LDS atomics.
__global__ __launch_bounds__(256) void k_agg1(const int* __restrict__ rec,
                                              const int* __restrict__ bsum,
                                              const float* __restrict__ dinv,
                                              const float* __restrict__ T1,
                                              const float* __restrict__ b1,
                                              const float* __restrict__ W2,
                                              float* __restrict__ T2) {
  __shared__ float acc[64 * APAD];
  __shared__ float dloc[64];
  int k = blockIdx.x;
  int n0 = k << BSH;
  int nmax = min(64, N_NODES - n0);
  int t = threadIdx.x;
  if (t < nmax) dloc[t] = dinv[n0 + t];
  for (int idx = t; idx < nmax * 16; idx += 256) {
    int n = idx >> 4, c = idx & 15;
    acc[n * APAD + c] = T1[(size_t)(n0 + n) * 16 + c];   // self loop (raw t1')
  }
  __syncthreads();
  int q = t & 3;
  int r = bsum[k] + (t >> 2);
  int end = bsum[k + 1];
  for (; r + 64 < end; r += 128) {
    int v0 = rec[r];
    int v1 = rec[r + 64];
    float4 u0 = *(const float4*)(T1 + (size_t)(v0 >> BSH) * 16 + q * 4);
    float4 u1 = *(const float4*)(T1 + (size_t)(v1 >> BSH) * 16 + q * 4);
    float* a0 = &acc[(v0 & 63) * APAD + q * 4];
    float* a1 = &acc[(v1 & 63) * APAD + q * 4];
    atomicAdd(a0 + 0, u0.x); atomicAdd(a0 + 1, u0.y);
    atomicAdd(a0 + 2, u0.z); atomicAdd(a0 + 3, u0.w);
    atomicAdd(a1 + 0, u1.x); atomicAdd(a1 + 1, u1.y);
    atomicAdd(a1 + 2, u1.z); atomicAdd(a1 + 3, u1.w);
  }
  if (r < end) {
    int v = rec[r];
    float4 u = *(const float4*)(T1 + (size_t)(v >> BSH) * 16 + q * 4);
    float* a = &acc[(v & 63) * APAD + q * 4];
    atomicAdd(a + 0, u.x); atomicAdd(a + 1, u.y);
    atomicAdd(a + 2, u.z); atomicAdd(a + 3, u.w);
  }
  __syncthreads();
  if (t < nmax) {
    float dd = dloc[t];
    float a0 = 0.f, a1 = 0.f;
#pragma unroll
    for (int c = 0; c < 16; ++c) {
      float hv = fmaxf(fmaf(dd, acc[t * APAD + c], b1[c]), 0.f);
      a0 = fmaf(hv, W2[c * 2 + 0], a0);
      a1 = fmaf(hv, W2[c * 2 + 1], a1);
    }
    T2[(size_t)(n0 + t) * 2 + 0] = dd * a0;   // t2' = dinv * t2
    T2[(size_t)(n0 + t) * 2 + 1] = dd * a1;
  }
}

// ---------------- layer-2 aggregation -> o2 ----------------
__global__ __launch_bounds__(256) void k_agg2(const int* __restrict__ rec,
                                              const int* __restrict__ bsum,
                                              const float* __restrict__ dinv,
                                              const float* __restrict__ T2,
                                              float* __restrict__ O2) {
  __shared__ float acc[64 * 3];
  __shared__ float dloc[64];
  int k = blockIdx.x;
  int n0 = k << BSH;
  int nmax = min(64, N_NODES - n0);
  int t = threadIdx.x;
  if (t < nmax) dloc[t] = dinv[n0 + t];
  if (t < nmax * 2) {
    int n = t >> 1, c = t & 1;
    acc[n * 3 + c] = T2[(size_t)(n0 + n) * 2 + c];
  }
  __syncthreads();
  int c = t & 1;
  int r = bsum[k] + (t >> 1);
  int end = bsum[k + 1];
  for (; r + 128 < end; r += 256) {
    int v0 = rec[r];
    int v1 = rec[r + 128];
    float u0 = T2[(size_t)(v0 >> BSH) * 2 + c];
    float u1 = T2[(size_t)(v1 >> BSH) * 2 + c];
    atomicAdd(&acc[(v0 & 63) * 3 + c], u0);
    atomicAdd(&acc[(v1 & 63) * 3 + c], u1);
  }
  if (r < end) {
    int v = rec[r];
    atomicAdd(&acc[(v & 63) * 3 + c], T2[(size_t)(v >> BSH) * 2 + c]);
  }
  __syncthreads();
  if (t < nmax) {
    O2[(size_t)(n0 + t) * 2 + 0] = dloc[t] * acc[t * 3 + 0];
    O2[(size_t)(n0 + t) * 2 + 1] = dloc[t] * acc[t * 3 + 1];
  }
}

// ---------------- pooling (batch sorted -> wave fast path) ----------------
__global__ __launch_bounds__(256) void k_pool(const float* __restrict__ O2,
                                              const int* __restrict__ batch,
                                              float* __restrict__ pool,
                                              float* __restrict__ gcnt) {
  int i = blockIdx.x * 256 + threadIdx.x;
  bool valid = i < N_NODES;
  int b = valid ? batch[i] : -1;
  float vx = 0.f, vy = 0.f;
  if (valid) {
    vx = O2[(size_t)i * 2 + 0];
    vy = O2[(size_t)i * 2 + 1];
  }
  int b0 = __shfl(b, 0);
  if (__all(b == b0)) {
    if (b0 >= 0) {
#pragma unroll
      for (int o = 32; o > 0; o >>= 1) {
        vx += __shfl_xor(vx, o);
        vy += __shfl_xor(vy, o);
      }
      if ((threadIdx.x & 63) == 0) {
        atomicAdd(&pool[b0 * 2 + 0], vx);
        atomicAdd(&pool[b0 * 2 + 1], vy);
        atomicAdd(&gcnt[b0], 64.0f);
      }
    }
  } else if (valid) {
    atomicAdd(&pool[b * 2 + 0], vx);
    atomicAdd(&pool[b * 2 + 1], vy);
    atomicAdd(&gcnt[b], 1.0f);
  }
}

// ---------------- final ----------------
__global__ __launch_bounds__(256) void k_final(const float* __restrict__ pool,
                                               const float* __restrict__ gcnt,
                                               const float* __restrict__ b2,
                                               float* __restrict__ out) {
  int g = threadIdx.x;
  if (g < NGR) {
    float c = fmaxf(gcnt[g], 1.0f);
    float p0 = pool[g * 2 + 0] / c + b2[0];
    float p1 = pool[g * 2 + 1] / c + b2[1];
    float m = fmaxf(p0, p1);
    float l = logf(expf(p0 - m) + expf(p1 - m));
    out[g * 2 + 0] = p0 - m - l;
    out[g * 2 + 1] = p1 - m - l;
  }
}

extern "C" void kernel_launch(void* const* d_in, const int* in_sizes, int n_in,
                              void* d_out, int out_size, void* d_ws, size_t ws_size,
                              hipStream_t stream) {
  const float* x  = (const float*)d_in[0];
  const float* W1 = (const float*)d_in[1];
  const float* b1 = (const float*)d_in[2];
  const float* W2 = (const float*)d_in[3];
  const float* b2 = (const float*)d_in[4];
  const int*   ei = (const int*)d_in[5];
  const int*   bt = (const int*)d_in[6];
  float* out = (float*)d_out;

  char* ws = (char*)d_ws;
  int*   bintot = (int*)ws;    ws += (size_t)NBIN * 4;
  int*   bincur = (int*)ws;    ws += (size_t)NBIN * 4;
  float* pool   = (float*)ws;  ws += 2 * NGR * 4;
  float* gcnt   = (float*)ws;  ws += NGR * 4;       // [bintot..gcnt] one memset
  int*   bsum   = (int*)ws;    ws += (size_t)(NBIN + 1) * 4;
  float* dinv   = (float*)ws;  ws += (size_t)N_NODES * 4;
  int*   rec    = (int*)ws;    ws += (size_t)N_EDGES * 4;
  float* t1     = (float*)ws;  ws += (size_t)N_NODES * 16 * 4;
  float* t2     = (float*)ws;  ws += (size_t)N_NODES * 2 * 4;
  float* o2     = (float*)ws;  ws += (size_t)N_NODES * 2 * 4;

  hipMemsetAsync(bintot, 0, (size_t)(2 * NBIN + 3 * NGR) * 4, stream);

  k_binhist <<<KBB, 256, 0, stream>>>(ei, bintot);
  k_scanbins<<<1, 1024, 0, stream>>>(bintot, bsum);
  k_bin     <<<KBB, 256, 0, stream>>>(ei, bsum, bincur, rec);
  k_dinv    <<<NBIN, 256, 0, stream>>>(rec, bsum, dinv);
  k_gemm1   <<<(N_NODES + 127) / 128, 128, 0, stream>>>(x, W1, dinv, t1);
  k_agg1    <<<NBIN, 256, 0, stream>>>(rec, bsum, dinv, t1, b1, W2, t2);
  k_agg2    <<<NBIN, 256, 0, stream>>>(rec, bsum, dinv, t2, o2);
  k_pool    <<<(N_NODES + 255) / 256, 256, 0, stream>>>(o2, bt, pool, gcnt);
  k_final   <<<1, 256, 0, stream>>>(pool, gcnt, b2, out);
}

// Round 6
// 289.853 us; speedup vs baseline: 3.3151x; 1.8103x over previous
//
#include <hip/hip_runtime.h>
#include <hip/hip_fp16.h>

#define N_NODES 100000
#define N_EDGES 3200000
#define F_INN 512
#define NGR 256
#define BSH 6                    // bin = dst >> 6 (64 nodes per bin)
#define NBIN 1563                // ceil(N_NODES/64)
#define KBB 256                  // binning blocks
#define CHUNK (N_EDGES / KBB)    // 12500 exactly

// ---------------- per-bin totals via LDS histograms ----------------
__global__ __launch_bounds__(256) void k_binhist(const int* __restrict__ ei,
                                                 int* __restrict__ bintot) {
  __shared__ int h[NBIN];
  for (int t = threadIdx.x; t < NBIN; t += 256) h[t] = 0;
  __syncthreads();
  int e0 = blockIdx.x * CHUNK;
  for (int i = threadIdx.x; i < CHUNK; i += 256)
    atomicAdd(&h[ei[N_EDGES + e0 + i] >> BSH], 1);
  __syncthreads();
  for (int t = threadIdx.x; t < NBIN; t += 256)
    if (h[t]) atomicAdd(&bintot[t], h[t]);
}

// ---------------- exclusive scan of NBIN bin totals ----------------
__global__ __launch_bounds__(1024) void k_scanbins(const int* __restrict__ bintot,
                                                   int* __restrict__ bsum) {
  __shared__ int s[1024];
  int t = threadIdx.x;
  int i0 = 2 * t, i1 = 2 * t + 1;
  int a = (i0 < NBIN) ? bintot[i0] : 0;
  int b = (i1 < NBIN) ? bintot[i1] : 0;
  s[t] = a + b;
  __syncthreads();
  for (int o = 1; o < 1024; o <<= 1) {
    int add = (t >= o) ? s[t - o] : 0;
    __syncthreads();
    s[t] += add;
    __syncthreads();
  }
  int excl = t ? s[t - 1] : 0;
  if (i0 <= NBIN) bsum[i0] = excl;
  if (i1 <= NBIN) bsum[i1] = excl + a;
}

// ---------------- binning: rec[bin segment] = (src<<6)|(dst&63) ----------------
__global__ __launch_bounds__(256) void k_bin(const int* __restrict__ ei,
                                             const int* __restrict__ bsum,
                                             int* __restrict__ bincur,
                                             int* __restrict__ rec) {
  __shared__ int h[NBIN];
  __shared__ int base[NBIN];
  for (int t = threadIdx.x; t < NBIN; t += 256) h[t] = 0;
  __syncthreads();
  int e0 = blockIdx.x * CHUNK;
  for (int i = threadIdx.x; i < CHUNK; i += 256)
    atomicAdd(&h[ei[N_EDGES + e0 + i] >> BSH], 1);
  __syncthreads();
  for (int t = threadIdx.x; t < NBIN; t += 256) {
    int c = h[t];
    base[t] = bsum[t] + (c ? atomicAdd(&bincur[t], c) : 0);
    h[t] = 0;
  }
  __syncthreads();
  for (int i = threadIdx.x; i < CHUNK; i += 256) {
    int s = ei[e0 + i];
    int d = ei[N_EDGES + e0 + i];
    int k = d >> BSH;
    int pos = base[k] + atomicAdd(&h[k], 1);
    rec[pos] = (s << BSH) | (d & 63);
  }
}

// ---------------- per-bin counting sort by dst + nstart + dinv ----------------
__global__ __launch_bounds__(256) void k_binsort(const int* __restrict__ rec,
                                                 const int* __restrict__ bsum,
                                                 int* __restrict__ rec2,
                                                 int* __restrict__ nstart,
                                                 float* __restrict__ dinv) {
  __shared__ int h[64], excl[64], cur[64];
  int k = blockIdx.x, t = threadIdx.x;
  if (t < 64) h[t] = 0;
  __syncthreads();
  int start = bsum[k], end = bsum[k + 1];
  for (int r = start + t; r < end; r += 256)
    atomicAdd(&h[rec[r] & 63], 1);
  __syncthreads();
  if (t < 64) {                         // wave 0: shuffle inclusive scan
    int v = h[t];
    int sc = v;
#pragma unroll
    for (int o = 1; o < 64; o <<= 1) {
      int u = __shfl_up(sc, o);
      if (t >= o) sc += u;
    }
    int ex = sc - v;
    excl[t] = ex;
    cur[t] = 0;
    int node = (k << BSH) + t;
    nstart[node] = start + ex;
    if (node < N_NODES) dinv[node] = rsqrtf((float)v + 1.0f);
  }
  if (k == NBIN - 1 && t == 0) nstart[NBIN * 64] = N_EDGES;
  __syncthreads();
  for (int r = start + t; r < end; r += 256) {
    int v = rec[r];
    int dl = v & 63;
    int pos = start + excl[dl] + atomicAdd(&cur[dl], 1);
    rec2[pos] = v;
  }
}

// ---------------- GEMM1: t1' = fp16( dinv * (X @ W1) ) ----------------
__global__ __launch_bounds__(128) void k_gemm1(const float* __restrict__ X,
                                               const float* __restrict__ W,
                                               const float* __restrict__ dinv,
                                               __half* __restrict__ T1h) {
  __shared__ float Ws[64 * 16];
  __shared__ float Xs[2][64 * 65];
  const int wave = threadIdx.x >> 6;
  const int lane = threadIdx.x & 63;
  const int rowBase = blockIdx.x * 128 + wave * 64;
  const int myRow = rowBase + lane;

  float acc[16];
#pragma unroll
  for (int j = 0; j < 16; ++j) acc[j] = 0.f;

  for (int kt = 0; kt < F_INN; kt += 64) {
    {
      int t = threadIdx.x;
      float4 w0 = *(const float4*)(W + kt * 16 + t * 8);
      float4 w1 = *(const float4*)(W + kt * 16 + t * 8 + 4);
      *(float4*)(&Ws[t * 8]) = w0;
      *(float4*)(&Ws[t * 8 + 4]) = w1;
    }
#pragma unroll
    for (int i = 0; i < 16; ++i) {
      int f = i * 64 + lane;
      int r = f >> 4;
      int kq = f & 15;
      int gr = rowBase + r;
      float4 v = make_float4(0.f, 0.f, 0.f, 0.f);
      if (gr < N_NODES) v = *(const float4*)(X + (size_t)gr * F_INN + kt + kq * 4);
      float* p = &Xs[wave][r * 65 + kq * 4];
      p[0] = v.x; p[1] = v.y; p[2] = v.z; p[3] = v.w;
    }
    __syncthreads();
#pragma unroll 8
    for (int k = 0; k < 64; ++k) {
      float xv = Xs[wave][lane * 65 + k];
#pragma unroll
      for (int j = 0; j < 16; ++j) acc[j] = fmaf(xv, Ws[k * 16 + j], acc[j]);
    }
    __syncthreads();
  }

  if (myRow < N_NODES) {
    float di = dinv[myRow];
    __half hbuf[16];
#pragma unroll
    for (int j = 0; j < 16; ++j) hbuf[j] = __float2half(di * acc[j]);
    uint4* dst = (uint4*)(T1h + (size_t)myRow * 16);
    dst[0] = ((uint4*)hbuf)[0];
    dst[1] = ((uint4*)hbuf)[1];
  }
}

// ---------------- layer-1 CSR gather + bias/ReLU/W2 fused -> t2' = dinv*t2 ----------------
// thread = (node, quarter): register accumulation, zero atomics.
__global__ __launch_bounds__(256) void k_agg1(const int* __restrict__ rec2,
                                              const int* __restrict__ nstart,
                                              const float* __restrict__ dinv,
                                              const __half* __restrict__ T1h,
                                              const float* __restrict__ b1,
                                              const float* __restrict__ W2,
                                              float* __restrict__ T2) {
  __shared__ float accs[64 * 17];
  int k = blockIdx.x, t = threadIdx.x;
  int n0 = k << BSH;
  int node = n0 + (t >> 2);
  int q = t & 3;
  bool nvalid = node < N_NODES;
  float a0 = 0.f, a1 = 0.f, a2 = 0.f, a3 = 0.f;
  int r = 0, e = 0;
  if (nvalid) {
    r = nstart[node];
    e = nstart[node + 1];
    uint2 u = *(const uint2*)(T1h + (size_t)node * 16 + q * 4);   // self loop
    float2 f0 = __half22float2(*reinterpret_cast<__half2*>(&u.x));
    float2 f1 = __half22float2(*reinterpret_cast<__half2*>(&u.y));
    a0 = f0.x; a1 = f0.y; a2 = f1.x; a3 = f1.y;
  }
  for (; r + 1 < e; r += 2) {
    int v0 = rec2[r], v1 = rec2[r + 1];
    uint2 ua = *(const uint2*)(T1h + (size_t)(v0 >> BSH) * 16 + q * 4);
    uint2 ub = *(const uint2*)(T1h + (size_t)(v1 >> BSH) * 16 + q * 4);
    float2 fa0 = __half22float2(*reinterpret_cast<__half2*>(&ua.x));
    float2 fa1 = __half22float2(*reinterpret_cast<__half2*>(&ua.y));
    float2 fb0 = __half22float2(*reinterpret_cast<__half2*>(&ub.x));
    float2 fb1 = __half22float2(*reinterpret_cast<__half2*>(&ub.y));
    a0 += fa0.x + fb0.x; a1 += fa0.y + fb0.y;
    a2 += fa1.x + fb1.x; a3 += fa1.y + fb1.y;
  }
  if (r < e) {
    int v = rec2[r];
    uint2 u = *(const uint2*)(T1h + (size_t)(v >> BSH) * 16 + q * 4);
    float2 f0 = __half22float2(*reinterpret_cast<__half2*>(&u.x));
    float2 f1 = __half22float2(*reinterpret_cast<__half2*>(&u.y));
    a0 += f0.x; a1 += f0.y; a2 += f1.x; a3 += f1.y;
  }
  float dd = nvalid ? dinv[node] : 0.f;
  float* row = &accs[(t >> 2) * 17 + q * 4];
  row[0] = dd * a0; row[1] = dd * a1; row[2] = dd * a2; row[3] = dd * a3;
  __syncthreads();
  if (t < 64) {
    int n = n0 + t;
    if (n < N_NODES) {
      float dd2 = dinv[n];
      float s0 = 0.f, s1 = 0.f;
#pragma unroll
      for (int c = 0; c < 16; ++c) {
        float hv = fmaxf(accs[t * 17 + c] + b1[c], 0.f);
        s0 = fmaf(hv, W2[c * 2 + 0], s0);
        s1 = fmaf(hv, W2[c * 2 + 1], s1);
      }
      T2[(size_t)n * 2 + 0] = dd2 * s0;   // t2' = dinv * t2
      T2[(size_t)n * 2 + 1] = dd2 * s1;
    }
  }
}

// ---------------- layer-2 CSR gather -> o2 ----------------
__global__ __launch_bounds__(128) void k_agg2(const int* __restrict__ rec2,
                                              const int* __restrict__ nstart,
                                              const float* __restrict__ dinv,
                                              const float* __restrict__ T2,
                                              float* __restrict__ O2) {
  int k = blockIdx.x, t = threadIdx.x;
  int n0 = k << BSH;
  int node = n0 + (t >> 1);
  int c = t & 1;
  if (node >= N_NODES) return;
  int r = nstart[node], e = nstart[node + 1];
  float acc = T2[(size_t)node * 2 + c];         // self loop
  for (; r + 1 < e; r += 2) {
    int v0 = rec2[r], v1 = rec2[r + 1];
    acc += T2[(size_t)(v0 >> BSH) * 2 + c] + T2[(size_t)(v1 >> BSH) * 2 + c];
  }
  if (r < e) acc += T2[(size_t)(rec2[r] >> BSH) * 2 + c];
  O2[(size_t)node * 2 + c] = dinv[node] * acc;
}

// ---------------- pooling (batch sorted -> wave fast path) ----------------
__global__ __launch_bounds__(256) void k_pool(const float* __restrict__ O2,
                                              const int* __restrict__ batch,
                                              float* __restrict__ pool,
                                              float* __restrict__ gcnt) {
  int i = blockIdx.x * 256 + threadIdx.x;
  bool valid = i < N_NODES;
  int b = valid ? batch[i] : -1;
  float vx = 0.f, vy = 0.f;
  if (valid) {
    vx = O2[(size_t)i * 2 + 0];
    vy = O2[(size_t)i * 2 + 1];
  }
  int b0 = __shfl(b, 0);
  if (__all(b == b0)) {
    if (b0 >= 0) {
#pragma unroll
      for (int o = 32; o > 0; o >>= 1) {
        vx += __shfl_xor(vx, o);
        vy += __shfl_xor(vy, o);
      }
      if ((threadIdx.x & 63) == 0) {
        atomicAdd(&pool[b0 * 2 + 0], vx);
        atomicAdd(&pool[b0 * 2 + 1], vy);
        atomicAdd(&gcnt[b0], 64.0f);
      }
    }
  } else if (valid) {
    atomicAdd(&pool[b * 2 + 0], vx);
    atomicAdd(&pool[b * 2 + 1], vy);
    atomicAdd(&gcnt[b], 1.0f);
  }
}

// ---------------- final ----------------
__global__ __launch_bounds__(256) void k_final(const float* __restrict__ pool,
                                               const float* __restrict__ gcnt,
                                               const float* __restrict__ b2,
                                               float* __restrict__ out) {
  int g = threadIdx.x;
  if (g < NGR) {
    float c = fmaxf(gcnt[g], 1.0f);
    float p0 = pool[g * 2 + 0] / c + b2[0];
    float p1 = pool[g * 2 + 1] / c + b2[1];
    float m = fmaxf(p0, p1);
    float l = logf(expf(p0 - m) + expf(p1 - m));
    out[g * 2 + 0] = p0 - m - l;
    out[g * 2 + 1] = p1 - m - l;
  }
}

extern "C" void kernel_launch(void* const* d_in, const int* in_sizes, int n_in,
                              void* d_out, int out_size, void* d_ws, size_t ws_size,
                              hipStream_t stream) {
  const float* x  = (const float*)d_in[0];
  const float* W1 = (const float*)d_in[1];
  const float* b1 = (const float*)d_in[2];
  const float* W2 = (const float*)d_in[3];
  const float* b2 = (const float*)d_in[4];
  const int*   ei = (const int*)d_in[5];
  const int*   bt = (const int*)d_in[6];
  float* out = (float*)d_out;

  char* ws = (char*)d_ws;
  int*   bintot = (int*)ws;    ws += (size_t)NBIN * 4;
  int*   bincur = (int*)ws;    ws += (size_t)NBIN * 4;
  float* pool   = (float*)ws;  ws += 2 * NGR * 4;
  float* gcnt   = (float*)ws;  ws += NGR * 4;       // [bintot..gcnt] one memset
  int*   bsum   = (int*)ws;    ws += (size_t)(NBIN + 1) * 4;
  int*   nstart = (int*)ws;    ws += (size_t)(NBIN * 64 + 2) * 4;
  float* dinv   = (float*)ws;  ws += (size_t)N_NODES * 4;
  int*   rec    = (int*)ws;    ws += (size_t)N_EDGES * 4;
  int*   rec2   = (int*)ws;    ws += (size_t)N_EDGES * 4;
  __half* t1h   = (__half*)ws; ws += (size_t)N_NODES * 16 * 2;
  float* t2     = (float*)ws;  ws += (size_t)N_NODES * 2 * 4;
  float* o2     = (float*)ws;  ws += (size_t)N_NODES * 2 * 4;

  hipMemsetAsync(bintot, 0, (size_t)(2 * NBIN + 3 * NGR) * 4, stream);

  k_binhist <<<KBB, 256, 0, stream>>>(ei, bintot);
  k_scanbins<<<1, 1024, 0, stream>>>(bintot, bsum);
  k_bin     <<<KBB, 256, 0, stream>>>(ei, bsum, bincur, rec);
  k_binsort <<<NBIN, 256, 0, stream>>>(rec, bsum, rec2, nstart, dinv);
  k_gemm1   <<<(N_NODES + 127) / 128, 128, 0, stream>>>(x, W1, dinv, t1h);
  k_agg1    <<<NBIN, 256, 0, stream>>>(rec2, nstart, dinv, t1h, b1, W2, t2);
  k_agg2    <<<NBIN, 128, 0, stream>>>(rec2, nstart, dinv, t2, o2);
  k_pool    <<<(N_NODES + 255) / 256, 256, 0, stream>>>(o2, bt, pool, gcnt);
  k_final   <<<1, 256, 0, stream>>>(pool, gcnt, b2, out);
}

// Round 7
// 268.846 us; speedup vs baseline: 3.5741x; 1.0781x over previous
//
#include <hip/hip_runtime.h>
#include <hip/hip_fp16.h>

#define N_NODES 100000
#define N_EDGES 3200000
#define F_INN 512
#define NGR 256
#define BSH 6                    // bin = dst >> 6 (64 nodes per bin)
#define NBIN 1563                // ceil(N_NODES/64)
#define KBB 256                  // binning blocks
#define CHUNK (N_EDGES / KBB)    // 12500 exactly

// ---------------- per-bin totals via LDS histograms ----------------
__global__ __launch_bounds__(256) void k_binhist(const int* __restrict__ ei,
                                                 int* __restrict__ bintot) {
  __shared__ int h[NBIN];
  for (int t = threadIdx.x; t < NBIN; t += 256) h[t] = 0;
  __syncthreads();
  int e0 = blockIdx.x * CHUNK;
  for (int i = threadIdx.x; i < CHUNK; i += 256)
    atomicAdd(&h[ei[N_EDGES + e0 + i] >> BSH], 1);
  __syncthreads();
  for (int t = threadIdx.x; t < NBIN; t += 256)
    if (h[t]) atomicAdd(&bintot[t], h[t]);
}

// ---------------- exclusive scan of NBIN bin totals ----------------
__global__ __launch_bounds__(1024) void k_scanbins(const int* __restrict__ bintot,
                                                   int* __restrict__ bsum) {
  __shared__ int s[1024];
  int t = threadIdx.x;
  int i0 = 2 * t, i1 = 2 * t + 1;
  int a = (i0 < NBIN) ? bintot[i0] : 0;
  int b = (i1 < NBIN) ? bintot[i1] : 0;
  s[t] = a + b;
  __syncthreads();
  for (int o = 1; o < 1024; o <<= 1) {
    int add = (t >= o) ? s[t - o] : 0;
    __syncthreads();
    s[t] += add;
    __syncthreads();
  }
  int excl = t ? s[t - 1] : 0;
  if (i0 <= NBIN) bsum[i0] = excl;
  if (i1 <= NBIN) bsum[i1] = excl + a;
}

// ---------------- binning: rec[bin segment] = (src<<6)|(dst&63) ----------------
__global__ __launch_bounds__(256) void k_bin(const int* __restrict__ ei,
                                             const int* __restrict__ bsum,
                                             int* __restrict__ bincur,
                                             int* __restrict__ rec) {
  __shared__ int h[NBIN];
  __shared__ int base[NBIN];
  for (int t = threadIdx.x; t < NBIN; t += 256) h[t] = 0;
  __syncthreads();
  int e0 = blockIdx.x * CHUNK;
  for (int i = threadIdx.x; i < CHUNK; i += 256)
    atomicAdd(&h[ei[N_EDGES + e0 + i] >> BSH], 1);
  __syncthreads();
  for (int t = threadIdx.x; t < NBIN; t += 256) {
    int c = h[t];
    base[t] = bsum[t] + (c ? atomicAdd(&bincur[t], c) : 0);
    h[t] = 0;
  }
  __syncthreads();
  for (int i = threadIdx.x; i < CHUNK; i += 256) {
    int s = ei[e0 + i];
    int d = ei[N_EDGES + e0 + i];
    int k = d >> BSH;
    int pos = base[k] + atomicAdd(&h[k], 1);
    rec[pos] = (s << BSH) | (d & 63);
  }
}

// ---------------- per-bin counting sort by dst + nstart + dinv ----------------
__global__ __launch_bounds__(256) void k_binsort(const int* __restrict__ rec,
                                                 const int* __restrict__ bsum,
                                                 int* __restrict__ rec2,
                                                 int* __restrict__ nstart,
                                                 float* __restrict__ dinv) {
  __shared__ int h[64], excl[64], cur[64];
  int k = blockIdx.x, t = threadIdx.x;
  if (t < 64) h[t] = 0;
  __syncthreads();
  int start = bsum[k], end = bsum[k + 1];
  for (int r = start + t; r < end; r += 256)
    atomicAdd(&h[rec[r] & 63], 1);
  __syncthreads();
  if (t < 64) {                         // wave 0: shuffle inclusive scan
    int v = h[t];
    int sc = v;
#pragma unroll
    for (int o = 1; o < 64; o <<= 1) {
      int u = __shfl_up(sc, o);
      if (t >= o) sc += u;
    }
    int ex = sc - v;
    excl[t] = ex;
    cur[t] = 0;
    int node = (k << BSH) + t;
    nstart[node] = start + ex;
    if (node < N_NODES) dinv[node] = rsqrtf((float)v + 1.0f);
  }
  if (k == NBIN - 1 && t == 0) nstart[NBIN * 64] = N_EDGES;
  __syncthreads();
  for (int r = start + t; r < end; r += 256) {
    int v = rec[r];
    int dl = v & 63;
    int pos = start + excl[dl] + atomicAdd(&cur[dl], 1);
    rec2[pos] = v;
  }
}

// ---------------- GEMM1: t1' = fp16( dinv * (X @ W1) ) ----------------
// 256 threads / 64 rows; wave = output col-quarter; reg double-buffered staging.
__global__ __launch_bounds__(256) void k_gemm1(const float* __restrict__ X,
                                               const float* __restrict__ W,
                                               const float* __restrict__ dinv,
                                               __half* __restrict__ T1h) {
  __shared__ float Xs[64 * 65];       // 16.6 KB, pad 65 -> 2-way-free reads
  __shared__ float Ws[64 * 16];       // 4 KB
  const int t = threadIdx.x;
  const int row = t & 63;             // lane = row
  const int cq = t >> 6;              // wave = col quarter
  const int rowBase = blockIdx.x * 64;
  const int grow = rowBase + row;

  float4 xr[4];
  float4 wr;
  // prefetch tile 0
#pragma unroll
  for (int i = 0; i < 4; ++i) {
    int f = i * 256 + t;
    int r = f >> 4, kq = f & 15;
    int gr = rowBase + r;
    xr[i] = (gr < N_NODES) ? *(const float4*)(X + (size_t)gr * F_INN + kq * 4)
                           : make_float4(0.f, 0.f, 0.f, 0.f);
  }
  wr = *(const float4*)(W + (t >> 2) * 16 + (t & 3) * 4);

  float acc[4] = {0.f, 0.f, 0.f, 0.f};

  for (int tt = 0; tt < 8; ++tt) {
    // write staged regs to LDS
#pragma unroll
    for (int i = 0; i < 4; ++i) {
      int f = i * 256 + t;
      int r = f >> 4, kq = f & 15;
      float* p = &Xs[r * 65 + kq * 4];
      p[0] = xr[i].x; p[1] = xr[i].y; p[2] = xr[i].z; p[3] = xr[i].w;
    }
    *(float4*)(&Ws[(t >> 2) * 16 + (t & 3) * 4]) = wr;
    __syncthreads();
    // prefetch next tile (loads in flight during compute)
    if (tt < 7) {
      int kt = (tt + 1) * 64;
#pragma unroll
      for (int i = 0; i < 4; ++i) {
        int f = i * 256 + t;
        int r = f >> 4, kq = f & 15;
        int gr = rowBase + r;
        xr[i] = (gr < N_NODES) ? *(const float4*)(X + (size_t)gr * F_INN + kt + kq * 4)
                               : make_float4(0.f, 0.f, 0.f, 0.f);
      }
      wr = *(const float4*)(W + (size_t)(kt + (t >> 2)) * 16 + (t & 3) * 4);
    }
    // compute: 64 k x 4 cols
    const int c0 = cq * 4;
#pragma unroll 8
    for (int k = 0; k < 64; ++k) {
      float xv = Xs[row * 65 + k];
      const float* w = &Ws[k * 16 + c0];
      acc[0] = fmaf(xv, w[0], acc[0]);
      acc[1] = fmaf(xv, w[1], acc[1]);
      acc[2] = fmaf(xv, w[2], acc[2]);
      acc[3] = fmaf(xv, w[3], acc[3]);
    }
    __syncthreads();
  }

  if (grow < N_NODES) {
    float di = dinv[grow];
    __half h[4];
#pragma unroll
    for (int j = 0; j < 4; ++j) h[j] = __float2half(di * acc[j]);
    *(uint2*)(T1h + (size_t)grow * 16 + cq * 4) = *(uint2*)h;
  }
}

// ---------------- layer-1 CSR gather + bias/ReLU/W2 fused -> t2' = dinv*t2 ----------------
__global__ __launch_bounds__(256) void k_agg1(const int* __restrict__ rec2,
                                              const int* __restrict__ nstart,
                                              const float* __restrict__ dinv,
                                              const __half* __restrict__ T1h,
                                              const float* __restrict__ b1,
                                              const float* __restrict__ W2,
                                              float* __restrict__ T2) {
  __shared__ float accs[64 * 17];
  int k = blockIdx.x, t = threadIdx.x;
  int n0 = k << BSH;
  int node = n0 + (t >> 2);
  int q = t & 3;
  bool nvalid = node < N_NODES;
  float a0 = 0.f, a1 = 0.f, a2 = 0.f, a3 = 0.f;
  int r = 0, e = 0;
  if (nvalid) {
    r = nstart[node];
    e = nstart[node + 1];
    uint2 u = *(const uint2*)(T1h + (size_t)node * 16 + q * 4);   // self loop
    float2 f0 = __half22float2(*reinterpret_cast<__half2*>(&u.x));
    float2 f1 = __half22float2(*reinterpret_cast<__half2*>(&u.y));
    a0 = f0.x; a1 = f0.y; a2 = f1.x; a3 = f1.y;
  }
  for (; r + 1 < e; r += 2) {
    int v0 = rec2[r], v1 = rec2[r + 1];
    uint2 ua = *(const uint2*)(T1h + (size_t)(v0 >> BSH) * 16 + q * 4);
    uint2 ub = *(const uint2*)(T1h + (size_t)(v1 >> BSH) * 16 + q * 4);
    float2 fa0 = __half22float2(*reinterpret_cast<__half2*>(&ua.x));
    float2 fa1 = __half22float2(*reinterpret_cast<__half2*>(&ua.y));
    float2 fb0 = __half22float2(*reinterpret_cast<__half2*>(&ub.x));
    float2 fb1 = __half22float2(*reinterpret_cast<__half2*>(&ub.y));
    a0 += fa0.x + fb0.x; a1 += fa0.y + fb0.y;
    a2 += fa1.x + fb1.x; a3 += fa1.y + fb1.y;
  }
  if (r < e) {
    int v = rec2[r];
    uint2 u = *(const uint2*)(T1h + (size_t)(v >> BSH) * 16 + q * 4);
    float2 f0 = __half22float2(*reinterpret_cast<__half2*>(&u.x));
    float2 f1 = __half22float2(*reinterpret_cast<__half2*>(&u.y));
    a0 += f0.x; a1 += f0.y; a2 += f1.x; a3 += f1.y;
  }
  float dd = nvalid ? dinv[node] : 0.f;
  float* rowp = &accs[(t >> 2) * 17 + q * 4];
  rowp[0] = dd * a0; rowp[1] = dd * a1; rowp[2] = dd * a2; rowp[3] = dd * a3;
  __syncthreads();
  if (t < 64) {
    int n = n0 + t;
    if (n < N_NODES) {
      float dd2 = dinv[n];
      float s0 = 0.f, s1 = 0.f;
#pragma unroll
      for (int c = 0; c < 16; ++c) {
        float hv = fmaxf(accs[t * 17 + c] + b1[c], 0.f);
        s0 = fmaf(hv, W2[c * 2 + 0], s0);
        s1 = fmaf(hv, W2[c * 2 + 1], s1);
      }
      T2[(size_t)n * 2 + 0] = dd2 * s0;   // t2' = dinv * t2
      T2[(size_t)n * 2 + 1] = dd2 * s1;
    }
  }
}

// ---------------- layer-2 CSR gather -> o2 ----------------
__global__ __launch_bounds__(128) void k_agg2(const int* __restrict__ rec2,
                                              const int* __restrict__ nstart,
                                              const float* __restrict__ dinv,
                                              const float* __restrict__ T2,
                                              float* __restrict__ O2) {
  int k = blockIdx.x, t = threadIdx.x;
  int n0 = k << BSH;
  int node = n0 + (t >> 1);
  int c = t & 1;
  if (node >= N_NODES) return;
  int r = nstart[node], e = nstart[node + 1];
  float acc = T2[(size_t)node * 2 + c];         // self loop
  for (; r + 1 < e; r += 2) {
    int v0 = rec2[r], v1 = rec2[r + 1];
    acc += T2[(size_t)(v0 >> BSH) * 2 + c] + T2[(size_t)(v1 >> BSH) * 2 + c];
  }
  if (r < e) acc += T2[(size_t)(rec2[r] >> BSH) * 2 + c];
  O2[(size_t)node * 2 + c] = dinv[node] * acc;
}

// ---------------- pooling (batch sorted -> wave fast path) ----------------
__global__ __launch_bounds__(256) void k_pool(const float* __restrict__ O2,
                                              const int* __restrict__ batch,
                                              float* __restrict__ pool,
                                              float* __restrict__ gcnt) {
  int i = blockIdx.x * 256 + threadIdx.x;
  bool valid = i < N_NODES;
  int b = valid ? batch[i] : -1;
  float vx = 0.f, vy = 0.f;
  if (valid) {
    vx = O2[(size_t)i * 2 + 0];
    vy = O2[(size_t)i * 2 + 1];
  }
  int b0 = __shfl(b, 0);
  if (__all(b == b0)) {
    if (b0 >= 0) {
#pragma unroll
      for (int o = 32; o > 0; o >>= 1) {
        vx += __shfl_xor(vx, o);
        vy += __shfl_xor(vy, o);
      }
      if ((threadIdx.x & 63) == 0) {
        atomicAdd(&pool[b0 * 2 + 0], vx);
        atomicAdd(&pool[b0 * 2 + 1], vy);
        atomicAdd(&gcnt[b0], 64.0f);
      }
    }
  } else if (valid) {
    atomicAdd(&pool[b * 2 + 0], vx);
    atomicAdd(&pool[b * 2 + 1], vy);
    atomicAdd(&gcnt[b], 1.0f);
  }
}

// ---------------- final ----------------
__global__ __launch_bounds__(256) void k_final(const float* __restrict__ pool,
                                               const float* __restrict__ gcnt,
                                               const float* __restrict__ b2,
                                               float* __restrict__ out) {
  int g = threadIdx.x;
  if (g < NGR) {
    float c = fmaxf(gcnt[g], 1.0f);
    float p0 = pool[g * 2 + 0] / c + b2[0];
    float p1 = pool[g * 2 + 1] / c + b2[1];
    float m = fmaxf(p0, p1);
    float l = logf(expf(p0 - m) + expf(p1 - m));
    out[g * 2 + 0] = p0 - m - l;
    out[g * 2 + 1] = p1 - m - l;
  }
}

extern "C" void kernel_launch(void* const* d_in, const int* in_sizes, int n_in,
                              void* d_out, int out_size, void* d_ws, size_t ws_size,
                              hipStream_t stream) {
  const float* x  = (const float*)d_in[0];
  const float* W1 = (const float*)d_in[1];
  const float* b1 = (const float*)d_in[2];
  const float* W2 = (const float*)d_in[3];
  const float* b2 = (const float*)d_in[4];
  const int*   ei = (const int*)d_in[5];
  const int*   bt = (const int*)d_in[6];
  float* out = (float*)d_out;

  char* ws = (char*)d_ws;
  int*   bintot = (int*)ws;    ws += (size_t)NBIN * 4;
  int*   bincur = (int*)ws;    ws += (size_t)NBIN * 4;
  float* pool   = (float*)ws;  ws += 2 * NGR * 4;
  float* gcnt   = (float*)ws;  ws += NGR * 4;       // [bintot..gcnt] one memset
  int*   bsum   = (int*)ws;    ws += (size_t)(NBIN + 1) * 4;
  int*   nstart = (int*)ws;    ws += (size_t)(NBIN * 64 + 2) * 4;
  float* dinv   = (float*)ws;  ws += (size_t)N_NODES * 4;
  int*   rec    = (int*)ws;    ws += (size_t)N_EDGES * 4;
  int*   rec2   = (int*)ws;    ws += (size_t)N_EDGES * 4;
  __half* t1h   = (__half*)ws; ws += (size_t)N_NODES * 16 * 2;
  float* t2     = (float*)ws;  ws += (size_t)N_NODES * 2 * 4;
  float* o2     = (float*)ws;  ws += (size_t)N_NODES * 2 * 4;

  hipMemsetAsync(bintot, 0, (size_t)(2 * NBIN + 3 * NGR) * 4, stream);

  k_binhist <<<KBB, 256, 0, stream>>>(ei, bintot);
  k_scanbins<<<1, 1024, 0, stream>>>(bintot, bsum);
  k_bin     <<<KBB, 256, 0, stream>>>(ei, bsum, bincur, rec);
  k_binsort <<<NBIN, 256, 0, stream>>>(rec, bsum, rec2, nstart, dinv);
  k_gemm1   <<<NBIN, 256, 0, stream>>>(x, W1, dinv, t1h);
  k_agg1    <<<NBIN, 256, 0, stream>>>(rec2, nstart, dinv, t1h, b1, W2, t2);
  k_agg2    <<<NBIN, 128, 0, stream>>>(rec2, nstart, dinv, t2, o2);
  k_pool    <<<(N_NODES + 255) / 256, 256, 0, stream>>>(o2, bt, pool, gcnt);
  k_final   <<<1, 256, 0, stream>>>(pool, gcnt, b2, out);
}

// Round 8
// 248.461 us; speedup vs baseline: 3.8674x; 1.0820x over previous
//
#include <hip/hip_runtime.h>
#include <hip/hip_fp16.h>

#define N_NODES 100000
#define N_EDGES 3200000
#define F_INN 512
#define NGR 256
#define BSH 6                    // bin = dst >> 6 (64 nodes per bin)
#define NBIN 1563                // ceil(N_NODES/64)
#define KBB 256                  // binning blocks
#define CHUNK (N_EDGES / KBB)    // 12500 exactly
#define KPAD 136                 // bf16 LDS row stride (2-way-free b128 reads)

typedef __attribute__((ext_vector_type(8))) short bf16x8;
typedef __attribute__((ext_vector_type(4))) float f32x4;

__device__ __forceinline__ uint f2bf2(float a, float b) {
  uint ua = __float_as_uint(a), ub = __float_as_uint(b);
  uint ra = (ua + 0x7FFF + ((ua >> 16) & 1)) >> 16;
  uint rb = (ub + 0x7FFF + ((ub >> 16) & 1)) >> 16;
  return ra | (rb << 16);
}

// ---------------- per-bin totals via LDS histograms ----------------
__global__ __launch_bounds__(256) void k_binhist(const int* __restrict__ ei,
                                                 int* __restrict__ bintot) {
  __shared__ int h[NBIN];
  for (int t = threadIdx.x; t < NBIN; t += 256) h[t] = 0;
  __syncthreads();
  int e0 = blockIdx.x * CHUNK;
  for (int i = threadIdx.x; i < CHUNK; i += 256)
    atomicAdd(&h[ei[N_EDGES + e0 + i] >> BSH], 1);
  __syncthreads();
  for (int t = threadIdx.x; t < NBIN; t += 256)
    if (h[t]) atomicAdd(&bintot[t], h[t]);
}

// ---------------- exclusive scan of NBIN bin totals ----------------
__global__ __launch_bounds__(1024) void k_scanbins(const int* __restrict__ bintot,
                                                   int* __restrict__ bsum) {
  __shared__ int s[1024];
  int t = threadIdx.x;
  int i0 = 2 * t, i1 = 2 * t + 1;
  int a = (i0 < NBIN) ? bintot[i0] : 0;
  int b = (i1 < NBIN) ? bintot[i1] : 0;
  s[t] = a + b;
  __syncthreads();
  for (int o = 1; o < 1024; o <<= 1) {
    int add = (t >= o) ? s[t - o] : 0;
    __syncthreads();
    s[t] += add;
    __syncthreads();
  }
  int excl = t ? s[t - 1] : 0;
  if (i0 <= NBIN) bsum[i0] = excl;
  if (i1 <= NBIN) bsum[i1] = excl + a;
}

// ---------------- binning: rec[bin segment] = (src<<6)|(dst&63) ----------------
__global__ __launch_bounds__(256) void k_bin(const int* __restrict__ ei,
                                             const int* __restrict__ bsum,
                                             int* __restrict__ bincur,
                                             int* __restrict__ rec) {
  __shared__ int h[NBIN];
  __shared__ int base[NBIN];
  for (int t = threadIdx.x; t < NBIN; t += 256) h[t] = 0;
  __syncthreads();
  int e0 = blockIdx.x * CHUNK;
  for (int i = threadIdx.x; i < CHUNK; i += 256)
    atomicAdd(&h[ei[N_EDGES + e0 + i] >> BSH], 1);
  __syncthreads();
  for (int t = threadIdx.x; t < NBIN; t += 256) {
    int c = h[t];
    base[t] = bsum[t] + (c ? atomicAdd(&bincur[t], c) : 0);
    h[t] = 0;
  }
  __syncthreads();
  for (int i = threadIdx.x; i < CHUNK; i += 256) {
    int s = ei[e0 + i];
    int d = ei[N_EDGES + e0 + i];
    int k = d >> BSH;
    int pos = base[k] + atomicAdd(&h[k], 1);
    rec[pos] = (s << BSH) | (d & 63);
  }
}

// ---------------- per-bin counting sort by dst + nstart + dinv ----------------
__global__ __launch_bounds__(256) void k_binsort(const int* __restrict__ rec,
                                                 const int* __restrict__ bsum,
                                                 int* __restrict__ rec2,
                                                 int* __restrict__ nstart,
                                                 float* __restrict__ dinv) {
  __shared__ int h[64], excl[64], cur[64];
  int k = blockIdx.x, t = threadIdx.x;
  if (t < 64) h[t] = 0;
  __syncthreads();
  int start = bsum[k], end = bsum[k + 1];
  for (int r = start + t; r < end; r += 256)
    atomicAdd(&h[rec[r] & 63], 1);
  __syncthreads();
  if (t < 64) {                         // wave 0: shuffle inclusive scan
    int v = h[t];
    int sc = v;
#pragma unroll
    for (int o = 1; o < 64; o <<= 1) {
      int u = __shfl_up(sc, o);
      if (t >= o) sc += u;
    }
    int ex = sc - v;
    excl[t] = ex;
    cur[t] = 0;
    int node = (k << BSH) + t;
    nstart[node] = start + ex;
    if (node < N_NODES) dinv[node] = rsqrtf((float)v + 1.0f);
  }
  if (k == NBIN - 1 && t == 0) nstart[NBIN * 64] = N_EDGES;
  __syncthreads();
  for (int r = start + t; r < end; r += 256) {
    int v = rec[r];
    int dl = v & 63;
    int pos = start + excl[dl] + atomicAdd(&cur[dl], 1);
    rec2[pos] = v;
  }
}

// ---------------- W1 -> bf16 transpose Wt[16][512] ----------------
__global__ __launch_bounds__(256) void k_wt(const float* __restrict__ W,
                                            ushort* __restrict__ Wt) {
  int tid = blockIdx.x * 256 + threadIdx.x;
  if (tid < 16 * 512) {
    int n = tid >> 9;
    int k = tid & 511;
    uint u = __float_as_uint(W[k * 16 + n]);
    Wt[tid] = (ushort)((u + 0x7FFF + ((u >> 16) & 1)) >> 16);
  }
}

// ---------------- GEMM1 (MFMA): t1' = fp16( dinv * (X @ W1) ) ----------------
// 4 waves x 16 rows; A = X rows (bf16, LDS-staged), B = Wt rows (L2-hot global).
__global__ __launch_bounds__(256) void k_gemm1(const float* __restrict__ X,
                                               const ushort* __restrict__ Wt,
                                               const float* __restrict__ dinv,
                                               __half* __restrict__ T1h) {
  __shared__ ushort Xs[64 * KPAD];    // 17408 B
  const int t = threadIdx.x;
  const int lane = t & 63;
  const int w = t >> 6;
  const int rowBase = blockIdx.x * 64;
  const int c16 = lane & 15;          // A-row / B-col / C-col index
  const int g = lane >> 4;            // k-group

  f32x4 acc = {0.f, 0.f, 0.f, 0.f};

  for (int kt = 0; kt < F_INN; kt += 128) {
    __syncthreads();                  // previous tile's readers done
#pragma unroll
    for (int i = 0; i < 8; ++i) {
      int f = i * 256 + t;
      int r = f >> 5;
      int q = f & 31;
      int gr = rowBase + r;
      float4 v = (gr < N_NODES) ? *(const float4*)(X + (size_t)gr * F_INN + kt + q * 4)
                                : make_float4(0.f, 0.f, 0.f, 0.f);
      uint2 pk = make_uint2(f2bf2(v.x, v.y), f2bf2(v.z, v.w));
      *(uint2*)&Xs[r * KPAD + q * 4] = pk;
    }
    __syncthreads();
    const ushort* arow = &Xs[(w * 16 + c16) * KPAD + g * 8];
    const ushort* brow = Wt + c16 * 512 + kt + g * 8;
#pragma unroll
    for (int s = 0; s < 4; ++s) {
      bf16x8 a = *(const bf16x8*)(arow + s * 32);
      bf16x8 b = *(const bf16x8*)(brow + s * 32);
      acc = __builtin_amdgcn_mfma_f32_16x16x32_bf16(a, b, acc, 0, 0, 0);
    }
  }

  // C/D: col = lane&15, rows = w*16 + g*4 + j
  int rbase = rowBase + w * 16 + g * 4;
#pragma unroll
  for (int j = 0; j < 4; ++j) {
    int r = rbase + j;
    if (r < N_NODES)
      T1h[(size_t)r * 16 + c16] = __float2half(dinv[r] * acc[j]);
  }
}

// ---------------- layer-1 CSR gather + bias/ReLU/W2 fused -> t2' = dinv*t2 ----------------
__global__ __launch_bounds__(256) void k_agg1(const int* __restrict__ rec2,
                                              const int* __restrict__ nstart,
                                              const float* __restrict__ dinv,
                                              const __half* __restrict__ T1h,
                                              const float* __restrict__ b1,
                                              const float* __restrict__ W2,
                                              float* __restrict__ T2) {
  __shared__ float accs[64 * 17];
  int k = blockIdx.x, t = threadIdx.x;
  int n0 = k << BSH;
  int node = n0 + (t >> 2);
  int q = t & 3;
  bool nvalid = node < N_NODES;
  float a0 = 0.f, a1 = 0.f, a2 = 0.f, a3 = 0.f;
  int r = 0, e = 0;
  if (nvalid) {
    r = nstart[node];
    e = nstart[node + 1];
    uint2 u = *(const uint2*)(T1h + (size_t)node * 16 + q * 4);   // self loop
    float2 f0 = __half22float2(*reinterpret_cast<__half2*>(&u.x));
    float2 f1 = __half22float2(*reinterpret_cast<__half2*>(&u.y));
    a0 = f0.x; a1 = f0.y; a2 = f1.x; a3 = f1.y;
  }
  for (; r + 1 < e; r += 2) {
    int v0 = rec2[r], v1 = rec2[r + 1];
    uint2 ua = *(const uint2*)(T1h + (size_t)(v0 >> BSH) * 16 + q * 4);
    uint2 ub = *(const uint2*)(T1h + (size_t)(v1 >> BSH) * 16 + q * 4);
    float2 fa0 = __half22float2(*reinterpret_cast<__half2*>(&ua.x));
    float2 fa1 = __half22float2(*reinterpret_cast<__half2*>(&ua.y));
    float2 fb0 = __half22float2(*reinterpret_cast<__half2*>(&ub.x));
    float2 fb1 = __half22float2(*reinterpret_cast<__half2*>(&ub.y));
    a0 += fa0.x + fb0.x; a1 += fa0.y + fb0.y;
    a2 += fa1.x + fb1.x; a3 += fa1.y + fb1.y;
  }
  if (r < e) {
    int v = rec2[r];
    uint2 u = *(const uint2*)(T1h + (size_t)(v >> BSH) * 16 + q * 4);
    float2 f0 = __half22float2(*reinterpret_cast<__half2*>(&u.x));
    float2 f1 = __half22float2(*reinterpret_cast<__half2*>(&u.y));
    a0 += f0.x; a1 += f0.y; a2 += f1.x; a3 += f1.y;
  }
  float dd = nvalid ? dinv[node] : 0.f;
  float* rowp = &accs[(t >> 2) * 17 + q * 4];
  rowp[0] = dd * a0; rowp[1] = dd * a1; rowp[2] = dd * a2; rowp[3] = dd * a3;
  __syncthreads();
  if (t < 64) {
    int n = n0 + t;
    if (n < N_NODES) {
      float dd2 = dinv[n];
      float s0 = 0.f, s1 = 0.f;
#pragma unroll
      for (int c = 0; c < 16; ++c) {
        float hv = fmaxf(accs[t * 17 + c] + b1[c], 0.f);
        s0 = fmaf(hv, W2[c * 2 + 0], s0);
        s1 = fmaf(hv, W2[c * 2 + 1], s1);
      }
      T2[(size_t)n * 2 + 0] = dd2 * s0;   // t2' = dinv * t2
      T2[(size_t)n * 2 + 1] = dd2 * s1;
    }
  }
}

// ---------------- layer-2 CSR gather -> o2 ----------------
__global__ __launch_bounds__(128) void k_agg2(const int* __restrict__ rec2,
                                              const int* __restrict__ nstart,
                                              const float* __restrict__ dinv,
                                              const float* __restrict__ T2,
                                              float* __restrict__ O2) {
  int k = blockIdx.x, t = threadIdx.x;
  int n0 = k << BSH;
  int node = n0 + (t >> 1);
  int c = t & 1;
  if (node >= N_NODES) return;
  int r = nstart[node], e = nstart[node + 1];
  float acc = T2[(size_t)node * 2 + c];         // self loop
  for (; r + 1 < e; r += 2) {
    int v0 = rec2[r], v1 = rec2[r + 1];
    acc += T2[(size_t)(v0 >> BSH) * 2 + c] + T2[(size_t)(v1 >> BSH) * 2 + c];
  }
  if (r < e) acc += T2[(size_t)(rec2[r] >> BSH) * 2 + c];
  O2[(size_t)node * 2 + c] = dinv[node] * acc;
}

// ---------------- pooling (batch sorted -> wave fast path) ----------------
__global__ __launch_bounds__(256) void k_pool(const float* __restrict__ O2,
                                              const int* __restrict__ batch,
                                              float* __restrict__ pool,
                                              float* __restrict__ gcnt) {
  int i = blockIdx.x * 256 + threadIdx.x;
  bool valid = i < N_NODES;
  int b = valid ? batch[i] : -1;
  float vx = 0.f, vy = 0.f;
  if (valid) {
    vx = O2[(size_t)i * 2 + 0];
    vy = O2[(size_t)i * 2 + 1];
  }
  int b0 = __shfl(b, 0);
  if (__all(b == b0)) {
    if (b0 >= 0) {
#pragma unroll
      for (int o = 32; o > 0; o >>= 1) {
        vx += __shfl_xor(vx, o);
        vy += __shfl_xor(vy, o);
      }
      if ((threadIdx.x & 63) == 0) {
        atomicAdd(&pool[b0 * 2 + 0], vx);
        atomicAdd(&pool[b0 * 2 + 1], vy);
        atomicAdd(&gcnt[b0], 64.0f);
      }
    }
  } else if (valid) {
    atomicAdd(&pool[b * 2 + 0], vx);
    atomicAdd(&pool[b * 2 + 1], vy);
    atomicAdd(&gcnt[b], 1.0f);
  }
}

// ---------------- final ----------------
__global__ __launch_bounds__(256) void k_final(const float* __restrict__ pool,
                                               const float* __restrict__ gcnt,
                                               const float* __restrict__ b2,
                                               float* __restrict__ out) {
  int g = threadIdx.x;
  if (g < NGR) {
    float c = fmaxf(gcnt[g], 1.0f);
    float p0 = pool[g * 2 + 0] / c + b2[0];
    float p1 = pool[g * 2 + 1] / c + b2[1];
    float m = fmaxf(p0, p1);
    float l = logf(expf(p0 - m) + expf(p1 - m));
    out[g * 2 + 0] = p0 - m - l;
    out[g * 2 + 1] = p1 - m - l;
  }
}

extern "C" void kernel_launch(void* const* d_in, const int* in_sizes, int n_in,
                              void* d_out, int out_size, void* d_ws, size_t ws_size,
                              hipStream_t stream) {
  const float* x  = (const float*)d_in[0];
  const float* W1 = (const float*)d_in[1];
  const float* b1 = (const float*)d_in[2];
  const float* W2 = (const float*)d_in[3];
  const float* b2 = (const float*)d_in[4];
  const int*   ei = (const int*)d_in[5];
  const int*   bt = (const int*)d_in[6];
  float* out = (float*)d_out;

  char* ws = (char*)d_ws;
  int*   bintot = (int*)ws;    ws += (size_t)NBIN * 4;
  int*   bincur = (int*)ws;    ws += (size_t)NBIN * 4;
  float* pool   = (float*)ws;  ws += 2 * NGR * 4;
  float* gcnt   = (float*)ws;  ws += NGR * 4;       // [bintot..gcnt] one memset
  int*   bsum   = (int*)ws;    ws += (size_t)(NBIN + 1) * 4;
  int*   nstart = (int*)ws;    ws += (size_t)(NBIN * 64 + 2) * 4;
  float* dinv   = (float*)ws;  ws += (size_t)N_NODES * 4;
  ushort* wt    = (ushort*)ws; ws += (size_t)16 * 512 * 2;
  int*   rec    = (int*)ws;    ws += (size_t)N_EDGES * 4;
  int*   rec2   = (int*)ws;    ws += (size_t)N_EDGES * 4;
  __half* t1h   = (__half*)ws; ws += (size_t)N_NODES * 16 * 2;
  float* t2     = (float*)ws;  ws += (size_t)N_NODES * 2 * 4;
  float* o2     = (float*)ws;  ws += (size_t)N_NODES * 2 * 4;

  hipMemsetAsync(bintot, 0, (size_t)(2 * NBIN + 3 * NGR) * 4, stream);

  k_binhist <<<KBB, 256, 0, stream>>>(ei, bintot);
  k_wt      <<<32, 256, 0, stream>>>(W1, wt);
  k_scanbins<<<1, 1024, 0, stream>>>(bintot, bsum);
  k_bin     <<<KBB, 256, 0, stream>>>(ei, bsum, bincur, rec);
  k_binsort <<<NBIN, 256, 0, stream>>>(rec, bsum, rec2, nstart, dinv);
  k_gemm1   <<<NBIN, 256, 0, stream>>>(x, wt, dinv, t1h);
  k_agg1    <<<NBIN, 256, 0, stream>>>(rec2, nstart, dinv, t1h, b1, W2, t2);
  k_agg2    <<<NBIN, 128, 0, stream>>>(rec2, nstart, dinv, t2, o2);
  k_pool    <<<(N_NODES + 255) / 256, 256, 0, stream>>>(o2, bt, pool, gcnt);
  k_final   <<<1, 256, 0, stream>>>(pool, gcnt, b2, out);
}

// Round 9
// 240.696 us; speedup vs baseline: 3.9921x; 1.0323x over previous
//
#include <hip/hip_runtime.h>
#include <hip/hip_fp16.h>

#define N_NODES 100000
#define N_EDGES 3200000
#define F_INN 512
#define NGR 256
#define BSH 6                    // bin = dst >> 6 (64 nodes per bin)
#define NBIN 1563                // ceil(N_NODES/64)
#define KBB 256                  // binning blocks
#define CHUNK (N_EDGES / KBB)    // 12500 exactly

typedef __attribute__((ext_vector_type(8))) short bf16x8;
typedef __attribute__((ext_vector_type(4))) float f32x4;

__device__ __forceinline__ uint f2bf2(float a, float b) {
  uint ua = __float_as_uint(a), ub = __float_as_uint(b);
  uint ra = (ua + 0x7FFF + ((ua >> 16) & 1)) >> 16;
  uint rb = (ub + 0x7FFF + ((ub >> 16) & 1)) >> 16;
  return ra | (rb << 16);
}

// ---------------- per-bin totals via LDS histograms ----------------
__global__ __launch_bounds__(512) void k_binhist(const int* __restrict__ ei,
                                                 int* __restrict__ bintot) {
  __shared__ int h[NBIN];
  for (int t = threadIdx.x; t < NBIN; t += 512) h[t] = 0;
  __syncthreads();
  int e0 = blockIdx.x * CHUNK;
  for (int i = threadIdx.x; i < CHUNK; i += 512)
    atomicAdd(&h[ei[N_EDGES + e0 + i] >> BSH], 1);
  __syncthreads();
  for (int t = threadIdx.x; t < NBIN; t += 512)
    if (h[t]) atomicAdd(&bintot[t], h[t]);
}

// ---------------- block 0: exclusive scan of NBIN totals; blocks 1..8: W1->bf16 transpose ----------------
__global__ __launch_bounds__(1024) void k_scan_wt(const int* __restrict__ bintot,
                                                  int* __restrict__ bsum,
                                                  const float* __restrict__ W,
                                                  ushort* __restrict__ Wt) {
  if (blockIdx.x == 0) {
    __shared__ int s[1024];
    int t = threadIdx.x;
    int i0 = 2 * t, i1 = 2 * t + 1;
    int a = (i0 < NBIN) ? bintot[i0] : 0;
    int b = (i1 < NBIN) ? bintot[i1] : 0;
    s[t] = a + b;
    __syncthreads();
    for (int o = 1; o < 1024; o <<= 1) {
      int add = (t >= o) ? s[t - o] : 0;
      __syncthreads();
      s[t] += add;
      __syncthreads();
    }
    int excl = t ? s[t - 1] : 0;
    if (i0 <= NBIN) bsum[i0] = excl;
    if (i1 <= NBIN) bsum[i1] = excl + a;
  } else {
    int tid = (blockIdx.x - 1) * 1024 + threadIdx.x;
    if (tid < 16 * 512) {
      int n = tid >> 9;
      int k = tid & 511;
      uint u = __float_as_uint(W[k * 16 + n]);
      Wt[tid] = (ushort)((u + 0x7FFF + ((u >> 16) & 1)) >> 16);
    }
  }
}

// ---------------- binning: rec[bin segment] = (src<<6)|(dst&63) ----------------
__global__ __launch_bounds__(512) void k_bin(const int* __restrict__ ei,
                                             const int* __restrict__ bsum,
                                             int* __restrict__ bincur,
                                             int* __restrict__ rec) {
  __shared__ int h[NBIN];
  __shared__ int base[NBIN];
  for (int t = threadIdx.x; t < NBIN; t += 512) h[t] = 0;
  __syncthreads();
  int e0 = blockIdx.x * CHUNK;
  for (int i = threadIdx.x; i < CHUNK; i += 512)
    atomicAdd(&h[ei[N_EDGES + e0 + i] >> BSH], 1);
  __syncthreads();
  for (int t = threadIdx.x; t < NBIN; t += 512) {
    int c = h[t];
    base[t] = bsum[t] + (c ? atomicAdd(&bincur[t], c) : 0);
    h[t] = 0;
  }
  __syncthreads();
  for (int i = threadIdx.x; i < CHUNK; i += 512) {
    int s = ei[e0 + i];
    int d = ei[N_EDGES + e0 + i];
    int k = d >> BSH;
    int pos = base[k] + atomicAdd(&h[k], 1);
    rec[pos] = (s << BSH) | (d & 63);
  }
}

// ---------------- per-bin counting sort by dst + nstart + dinv ----------------
__global__ __launch_bounds__(256) void k_binsort(const int* __restrict__ rec,
                                                 const int* __restrict__ bsum,
                                                 int* __restrict__ rec2,
                                                 int* __restrict__ nstart,
                                                 float* __restrict__ dinv) {
  __shared__ int h[64], excl[64], cur[64];
  int k = blockIdx.x, t = threadIdx.x;
  if (t < 64) h[t] = 0;
  __syncthreads();
  int start = bsum[k], end = bsum[k + 1];
  for (int r = start + t; r < end; r += 256)
    atomicAdd(&h[rec[r] & 63], 1);
  __syncthreads();
  if (t < 64) {                         // wave 0: shuffle inclusive scan
    int v = h[t];
    int sc = v;
#pragma unroll
    for (int o = 1; o < 64; o <<= 1) {
      int u = __shfl_up(sc, o);
      if (t >= o) sc += u;
    }
    int ex = sc - v;
    excl[t] = ex;
    cur[t] = 0;
    int node = (k << BSH) + t;
    nstart[node] = start + ex;
    if (node < N_NODES) dinv[node] = rsqrtf((float)v + 1.0f);
  }
  if (k == NBIN - 1 && t == 0) nstart[NBIN * 64] = N_EDGES;
  __syncthreads();
  for (int r = start + t; r < end; r += 256) {
    int v = rec[r];
    int dl = v & 63;
    int pos = start + excl[dl] + atomicAdd(&cur[dl], 1);
    rec2[pos] = v;
  }
}

// ---------------- GEMM1 (MFMA, LDS-free): t1' = fp16( dinv * (X @ W1) ) ----------------
// Each lane streams its own A-row fragments straight from global (full line
// utilization: 64 lanes = 16 rows x 128 contiguous bytes per k-step). No
// __shared__, no barriers -> waves drift, continuous L3 stream.
__global__ __launch_bounds__(256) void k_gemm1(const float* __restrict__ X,
                                               const ushort* __restrict__ Wt,
                                               const float* __restrict__ dinv,
                                               __half* __restrict__ T1h) {
  const int t = threadIdx.x;
  const int lane = t & 63;
  const int w = t >> 6;
  const int c16 = lane & 15;          // A-row (stream) / B-col / C-col index
  const int g = lane >> 4;            // k-group
  const int arow = blockIdx.x * 64 + w * 16 + c16;
  const bool rv = arow < N_NODES;
  const float* xrow = X + (size_t)arow * F_INN + g * 8;
  const ushort* brow = Wt + c16 * 512 + g * 8;

  f32x4 acc = {0.f, 0.f, 0.f, 0.f};
#pragma unroll
  for (int ks = 0; ks < 16; ++ks) {   // 16 steps of K=32
    float4 v0 = rv ? *(const float4*)(xrow + ks * 32)     : make_float4(0.f, 0.f, 0.f, 0.f);
    float4 v1 = rv ? *(const float4*)(xrow + ks * 32 + 4) : make_float4(0.f, 0.f, 0.f, 0.f);
    uint au[4] = { f2bf2(v0.x, v0.y), f2bf2(v0.z, v0.w),
                   f2bf2(v1.x, v1.y), f2bf2(v1.z, v1.w) };
    bf16x8 a = *(const bf16x8*)au;
    bf16x8 b = *(const bf16x8*)(brow + ks * 32);
    acc = __builtin_amdgcn_mfma_f32_16x16x32_bf16(a, b, acc, 0, 0, 0);
  }

  // C/D: col = lane&15, rows = w*16 + g*4 + j
  int rbase = blockIdx.x * 64 + w * 16 + g * 4;
#pragma unroll
  for (int j = 0; j < 4; ++j) {
    int r = rbase + j;
    if (r < N_NODES)
      T1h[(size_t)r * 16 + c16] = __float2half(dinv[r] * acc[j]);
  }
}

// ---------------- layer-1 CSR gather + bias/ReLU/W2 fused -> t2' = dinv*t2 ----------------
__global__ __launch_bounds__(256) void k_agg1(const int* __restrict__ rec2,
                                              const int* __restrict__ nstart,
                                              const float* __restrict__ dinv,
                                              const __half* __restrict__ T1h,
                                              const float* __restrict__ b1,
                                              const float* __restrict__ W2,
                                              float* __restrict__ T2) {
  __shared__ float accs[64 * 17];
  int k = blockIdx.x, t = threadIdx.x;
  int n0 = k << BSH;
  int node = n0 + (t >> 2);
  int q = t & 3;
  bool nvalid = node < N_NODES;
  float a0 = 0.f, a1 = 0.f, a2 = 0.f, a3 = 0.f;
  int r = 0, e = 0;
  if (nvalid) {
    r = nstart[node];
    e = nstart[node + 1];
    uint2 u = *(const uint2*)(T1h + (size_t)node * 16 + q * 4);   // self loop
    float2 f0 = __half22float2(*reinterpret_cast<__half2*>(&u.x));
    float2 f1 = __half22float2(*reinterpret_cast<__half2*>(&u.y));
    a0 = f0.x; a1 = f0.y; a2 = f1.x; a3 = f1.y;
  }
  for (; r + 1 < e; r += 2) {
    int v0 = rec2[r], v1 = rec2[r + 1];
    uint2 ua = *(const uint2*)(T1h + (size_t)(v0 >> BSH) * 16 + q * 4);
    uint2 ub = *(const uint2*)(T1h + (size_t)(v1 >> BSH) * 16 + q * 4);
    float2 fa0 = __half22float2(*reinterpret_cast<__half2*>(&ua.x));
    float2 fa1 = __half22float2(*reinterpret_cast<__half2*>(&ua.y));
    float2 fb0 = __half22float2(*reinterpret_cast<__half2*>(&ub.x));
    float2 fb1 = __half22float2(*reinterpret_cast<__half2*>(&ub.y));
    a0 += fa0.x + fb0.x; a1 += fa0.y + fb0.y;
    a2 += fa1.x + fb1.x; a3 += fa1.y + fb1.y;
  }
  if (r < e) {
    int v = rec2[r];
    uint2 u = *(const uint2*)(T1h + (size_t)(v >> BSH) * 16 + q * 4);
    float2 f0 = __half22float2(*reinterpret_cast<__half2*>(&u.x));
    float2 f1 = __half22float2(*reinterpret_cast<__half2*>(&u.y));
    a0 += f0.x; a1 += f0.y; a2 += f1.x; a3 += f1.y;
  }
  float dd = nvalid ? dinv[node] : 0.f;
  float* rowp = &accs[(t >> 2) * 17 + q * 4];
  rowp[0] = dd * a0; rowp[1] = dd * a1; rowp[2] = dd * a2; rowp[3] = dd * a3;
  __syncthreads();
  if (t < 64) {
    int n = n0 + t;
    if (n < N_NODES) {
      float dd2 = dinv[n];
      float s0 = 0.f, s1 = 0.f;
#pragma unroll
      for (int c = 0; c < 16; ++c) {
        float hv = fmaxf(accs[t * 17 + c] + b1[c], 0.f);
        s0 = fmaf(hv, W2[c * 2 + 0], s0);
        s1 = fmaf(hv, W2[c * 2 + 1], s1);
      }
      T2[(size_t)n * 2 + 0] = dd2 * s0;   // t2' = dinv * t2
      T2[(size_t)n * 2 + 1] = dd2 * s1;
    }
  }
}

// ---------------- layer-2 CSR gather -> o2 ----------------
__global__ __launch_bounds__(128) void k_agg2(const int* __restrict__ rec2,
                                              const int* __restrict__ nstart,
                                              const float* __restrict__ dinv,
                                              const float* __restrict__ T2,
                                              float* __restrict__ O2) {
  int k = blockIdx.x, t = threadIdx.x;
  int n0 = k << BSH;
  int node = n0 + (t >> 1);
  int c = t & 1;
  if (node >= N_NODES) return;
  int r = nstart[node], e = nstart[node + 1];
  float acc = T2[(size_t)node * 2 + c];         // self loop
  for (; r + 1 < e; r += 2) {
    int v0 = rec2[r], v1 = rec2[r + 1];
    acc += T2[(size_t)(v0 >> BSH) * 2 + c] + T2[(size_t)(v1 >> BSH) * 2 + c];
  }
  if (r < e) acc += T2[(size_t)(rec2[r] >> BSH) * 2 + c];
  O2[(size_t)node * 2 + c] = dinv[node] * acc;
}

// ---------------- pooling (batch sorted -> wave fast path) ----------------
__global__ __launch_bounds__(256) void k_pool(const float* __restrict__ O2,
                                              const int* __restrict__ batch,
                                              float* __restrict__ pool,
                                              float* __restrict__ gcnt) {
  int i = blockIdx.x * 256 + threadIdx.x;
  bool valid = i < N_NODES;
  int b = valid ? batch[i] : -1;
  float vx = 0.f, vy = 0.f;
  if (valid) {
    vx = O2[(size_t)i * 2 + 0];
    vy = O2[(size_t)i * 2 + 1];
  }
  int b0 = __shfl(b, 0);
  if (__all(b == b0)) {
    if (b0 >= 0) {
#pragma unroll
      for (int o = 32; o > 0; o >>= 1) {
        vx += __shfl_xor(vx, o);
        vy += __shfl_xor(vy, o);
      }
      if ((threadIdx.x & 63) == 0) {
        atomicAdd(&pool[b0 * 2 + 0], vx);
        atomicAdd(&pool[b0 * 2 + 1], vy);
        atomicAdd(&gcnt[b0], 64.0f);
      }
    }
  } else if (valid) {
    atomicAdd(&pool[b * 2 + 0], vx);
    atomicAdd(&pool[b * 2 + 1], vy);
    atomicAdd(&gcnt[b], 1.0f);
  }
}

// ---------------- final ----------------
__global__ __launch_bounds__(256) void k_final(const float* __restrict__ pool,
                                               const float* __restrict__ gcnt,
                                               const float* __restrict__ b2,
                                               float* __restrict__ out) {
  int g = threadIdx.x;
  if (g < NGR) {
    float c = fmaxf(gcnt[g], 1.0f);
    float p0 = pool[g * 2 + 0] / c + b2[0];
    float p1 = pool[g * 2 + 1] / c + b2[1];
    float m = fmaxf(p0, p1);
    float l = logf(expf(p0 - m) + expf(p1 - m));
    out[g * 2 + 0] = p0 - m - l;
    out[g * 2 + 1] = p1 - m - l;
  }
}

extern "C" void kernel_launch(void* const* d_in, const int* in_sizes, int n_in,
                              void* d_out, int out_size, void* d_ws, size_t ws_size,
                              hipStream_t stream) {
  const float* x  = (const float*)d_in[0];
  const float* W1 = (const float*)d_in[1];
  const float* b1 = (const float*)d_in[2];
  const float* W2 = (const float*)d_in[3];
  const float* b2 = (const float*)d_in[4];
  const int*   ei = (const int*)d_in[5];
  const int*   bt = (const int*)d_in[6];
  float* out = (float*)d_out;

  char* ws = (char*)d_ws;
  int*   bintot = (int*)ws;    ws += (size_t)NBIN * 4;
  int*   bincur = (int*)ws;    ws += (size_t)NBIN * 4;
  float* pool   = (float*)ws;  ws += 2 * NGR * 4;
  float* gcnt   = (float*)ws;  ws += NGR * 4;       // [bintot..gcnt] one memset
  int*   bsum   = (int*)ws;    ws += (size_t)(NBIN + 1) * 4;
  int*   nstart = (int*)ws;    ws += (size_t)(NBIN * 64 + 2) * 4;
  float* dinv   = (float*)ws;  ws += (size_t)N_NODES * 4;
  ushort* wt    = (ushort*)ws; ws += (size_t)16 * 512 * 2;
  int*   rec    = (int*)ws;    ws += (size_t)N_EDGES * 4;
  int*   rec2   = (int*)ws;    ws += (size_t)N_EDGES * 4;
  __half* t1h   = (__half*)ws; ws += (size_t)N_NODES * 16 * 2;
  float* t2     = (float*)ws;  ws += (size_t)N_NODES * 2 * 4;
  float* o2     = (float*)ws;  ws += (size_t)N_NODES * 2 * 4;

  hipMemsetAsync(bintot, 0, (size_t)(2 * NBIN + 3 * NGR) * 4, stream);

  k_binhist <<<KBB, 512, 0, stream>>>(ei, bintot);
  k_scan_wt <<<9, 1024, 0, stream>>>(bintot, bsum, W1, wt);
  k_bin     <<<KBB, 512, 0, stream>>>(ei, bsum, bincur, rec);
  k_binsort <<<NBIN, 256, 0, stream>>>(rec, bsum, rec2, nstart, dinv);
  k_gemm1   <<<NBIN, 256, 0, stream>>>(x, wt, dinv, t1h);
  k_agg1    <<<NBIN, 256, 0, stream>>>(rec2, nstart, dinv, t1h, b1, W2, t2);
  k_agg2    <<<NBIN, 128, 0, stream>>>(rec2, nstart, dinv, t2, o2);
  k_pool    <<<(N_NODES + 255) / 256, 256, 0, stream>>>(o2, bt, pool, gcnt);
  k_final   <<<1, 256, 0, stream>>>(pool, gcnt, b2, out);
}

// Round 10
// 201.722 us; speedup vs baseline: 4.7634x; 1.1932x over previous
//
#include <hip/hip_runtime.h>
#include <hip/hip_fp16.h>

#define N_NODES 100000
#define N_EDGES 3200000
#define F_INN 512
#define NGR 256
#define BSH 6                    // bin = dst >> 6 (64 nodes per bin)
#define NBIN 1563                // ceil(N_NODES/64)
#define KBB 256                  // binning blocks
#define CHUNK (N_EDGES / KBB)    // 12500 exactly
#define CAP 2560                 // per-bin record capacity (mean 2048, +11 sigma)

typedef __attribute__((ext_vector_type(8))) short bf16x8;
typedef __attribute__((ext_vector_type(4))) float f32x4;

__device__ __forceinline__ uint f2bf2(float a, float b) {
  uint ua = __float_as_uint(a), ub = __float_as_uint(b);
  uint ra = (ua + 0x7FFF + ((ua >> 16) & 1)) >> 16;
  uint rb = (ub + 0x7FFF + ((ub >> 16) & 1)) >> 16;
  return ra | (rb << 16);
}

// ---------------- binning into fixed-capacity segments + W1 transpose ----------------
// blocks 0..KBB-1: rec[k*CAP + off] = (src<<6)|(dst&63). block KBB: Wt transpose.
__global__ __launch_bounds__(512) void k_bin(const int* __restrict__ ei,
                                             int* __restrict__ bincur,
                                             int* __restrict__ rec,
                                             const float* __restrict__ W,
                                             ushort* __restrict__ Wt) {
  if (blockIdx.x == KBB) {
    for (int tid = threadIdx.x; tid < 16 * 512; tid += 512) {
      int n = tid >> 9;
      int k = tid & 511;
      uint u = __float_as_uint(W[k * 16 + n]);
      Wt[tid] = (ushort)((u + 0x7FFF + ((u >> 16) & 1)) >> 16);
    }
    return;
  }
  __shared__ int h[NBIN];
  __shared__ int base[NBIN];
  for (int t = threadIdx.x; t < NBIN; t += 512) h[t] = 0;
  __syncthreads();
  int e0 = blockIdx.x * CHUNK;
  for (int i = threadIdx.x; i < CHUNK; i += 512)
    atomicAdd(&h[ei[N_EDGES + e0 + i] >> BSH], 1);
  __syncthreads();
  for (int t = threadIdx.x; t < NBIN; t += 512) {
    int c = h[t];
    base[t] = t * CAP + (c ? atomicAdd(&bincur[t], c) : 0);
    h[t] = 0;                       // reuse as local cursor
  }
  __syncthreads();
  for (int i = threadIdx.x; i < CHUNK; i += 512) {
    int s = ei[e0 + i];
    int d = ei[N_EDGES + e0 + i];
    int k = d >> BSH;
    int pos = base[k] + atomicAdd(&h[k], 1);
    rec[pos] = (s << BSH) | (d & 63);
  }
}

// ---------------- per-bin counting sort by dst + nstart/ncnt + dinv ----------------
__global__ __launch_bounds__(256) void k_binsort(const int* __restrict__ rec,
                                                 const int* __restrict__ bincur,
                                                 int* __restrict__ rec2,
                                                 int* __restrict__ nstart,
                                                 int* __restrict__ ncnt,
                                                 float* __restrict__ dinv) {
  __shared__ int h[64], excl[64], cur[64];
  int k = blockIdx.x, t = threadIdx.x;
  if (t < 64) h[t] = 0;
  __syncthreads();
  int start = k * CAP;
  int end = start + bincur[k];
  for (int r = start + t; r < end; r += 256)
    atomicAdd(&h[rec[r] & 63], 1);
  __syncthreads();
  if (t < 64) {                         // wave 0: shuffle inclusive scan
    int v = h[t];
    int sc = v;
#pragma unroll
    for (int o = 1; o < 64; o <<= 1) {
      int u = __shfl_up(sc, o);
      if (t >= o) sc += u;
    }
    int ex = sc - v;
    excl[t] = ex;
    cur[t] = 0;
    int node = (k << BSH) + t;
    if (node < N_NODES) {
      nstart[node] = start + ex;
      ncnt[node] = v;
      dinv[node] = rsqrtf((float)v + 1.0f);
    }
  }
  __syncthreads();
  for (int r = start + t; r < end; r += 256) {
    int v = rec[r];
    int dl = v & 63;
    int pos = start + excl[dl] + atomicAdd(&cur[dl], 1);
    rec2[pos] = v;
  }
}

// ---------------- GEMM1 (MFMA, LDS-free): t1' = fp16( dinv * (X @ W1) ) ----------------
__global__ __launch_bounds__(256) void k_gemm1(const float* __restrict__ X,
                                               const ushort* __restrict__ Wt,
                                               const float* __restrict__ dinv,
                                               __half* __restrict__ T1h) {
  const int t = threadIdx.x;
  const int lane = t & 63;
  const int w = t >> 6;
  const int c16 = lane & 15;          // A-row (stream) / B-col / C-col index
  const int g = lane >> 4;            // k-group
  const int arow = blockIdx.x * 64 + w * 16 + c16;
  const bool rv = arow < N_NODES;
  const float* xrow = X + (size_t)arow * F_INN + g * 8;
  const ushort* brow = Wt + c16 * 512 + g * 8;

  f32x4 acc = {0.f, 0.f, 0.f, 0.f};
#pragma unroll
  for (int ks = 0; ks < 16; ++ks) {   // 16 steps of K=32
    float4 v0 = rv ? *(const float4*)(xrow + ks * 32)     : make_float4(0.f, 0.f, 0.f, 0.f);
    float4 v1 = rv ? *(const float4*)(xrow + ks * 32 + 4) : make_float4(0.f, 0.f, 0.f, 0.f);
    uint au[4] = { f2bf2(v0.x, v0.y), f2bf2(v0.z, v0.w),
                   f2bf2(v1.x, v1.y), f2bf2(v1.z, v1.w) };
    bf16x8 a = *(const bf16x8*)au;
    bf16x8 b = *(const bf16x8*)(brow + ks * 32);
    acc = __builtin_amdgcn_mfma_f32_16x16x32_bf16(a, b, acc, 0, 0, 0);
  }

  int rbase = blockIdx.x * 64 + w * 16 + g * 4;
#pragma unroll
  for (int j = 0; j < 4; ++j) {
    int r = rbase + j;
    if (r < N_NODES)
      T1h[(size_t)r * 16 + c16] = __float2half(dinv[r] * acc[j]);
  }
}

// ---------------- layer-1 gather (LDS-staged records) + bias/ReLU/W2 -> t2' ----------------
__global__ __launch_bounds__(256) void k_agg1(const int* __restrict__ rec2,
                                              const int* __restrict__ bincur,
                                              const int* __restrict__ nstart,
                                              const int* __restrict__ ncnt,
                                              const float* __restrict__ dinv,
                                              const __half* __restrict__ T1h,
                                              const float* __restrict__ b1,
                                              const float* __restrict__ W2,
                                              float* __restrict__ T2) {
  __shared__ float accs[64 * 17];
  __shared__ int recs[CAP];
  int k = blockIdx.x, t = threadIdx.x;
  int n0 = k << BSH;
  int cnt = bincur[k];
  for (int i = t; i < cnt; i += 256) recs[i] = rec2[k * CAP + i];   // coalesced stage
  int node = n0 + (t >> 2);
  int q = t & 3;
  bool nvalid = node < N_NODES;
  float a0 = 0.f, a1 = 0.f, a2 = 0.f, a3 = 0.f;
  int r = 0, e = 0;
  if (nvalid) {
    r = nstart[node] - k * CAP;       // local offset into recs
    e = r + ncnt[node];
    uint2 u = *(const uint2*)(T1h + (size_t)node * 16 + q * 4);   // self loop
    float2 f0 = __half22float2(*reinterpret_cast<__half2*>(&u.x));
    float2 f1 = __half22float2(*reinterpret_cast<__half2*>(&u.y));
    a0 = f0.x; a1 = f0.y; a2 = f1.x; a3 = f1.y;
  }
  __syncthreads();
  for (; r + 1 < e; r += 2) {
    int v0 = recs[r], v1 = recs[r + 1];
    uint2 ua = *(const uint2*)(T1h + (size_t)(v0 >> BSH) * 16 + q * 4);
    uint2 ub = *(const uint2*)(T1h + (size_t)(v1 >> BSH) * 16 + q * 4);
    float2 fa0 = __half22float2(*reinterpret_cast<__half2*>(&ua.x));
    float2 fa1 = __half22float2(*reinterpret_cast<__half2*>(&ua.y));
    float2 fb0 = __half22float2(*reinterpret_cast<__half2*>(&ub.x));
    float2 fb1 = __half22float2(*reinterpret_cast<__half2*>(&ub.y));
    a0 += fa0.x + fb0.x; a1 += fa0.y + fb0.y;
    a2 += fa1.x + fb1.x; a3 += fa1.y + fb1.y;
  }
  if (r < e) {
    int v = recs[r];
    uint2 u = *(const uint2*)(T1h + (size_t)(v >> BSH) * 16 + q * 4);
    float2 f0 = __half22float2(*reinterpret_cast<__half2*>(&u.x));
    float2 f1 = __half22float2(*reinterpret_cast<__half2*>(&u.y));
    a0 += f0.x; a1 += f0.y; a2 += f1.x; a3 += f1.y;
  }
  float dd = nvalid ? dinv[node] : 0.f;
  float* rowp = &accs[(t >> 2) * 17 + q * 4];
  rowp[0] = dd * a0; rowp[1] = dd * a1; rowp[2] = dd * a2; rowp[3] = dd * a3;
  __syncthreads();
  if (t < 64) {
    int n = n0 + t;
    if (n < N_NODES) {
      float dd2 = dinv[n];
      float s0 = 0.f, s1 = 0.f;
#pragma unroll
      for (int c = 0; c < 16; ++c) {
        float hv = fmaxf(accs[t * 17 + c] + b1[c], 0.f);
        s0 = fmaf(hv, W2[c * 2 + 0], s0);
        s1 = fmaf(hv, W2[c * 2 + 1], s1);
      }
      T2[(size_t)n * 2 + 0] = dd2 * s0;   // t2' = dinv * t2
      T2[(size_t)n * 2 + 1] = dd2 * s1;
    }
  }
}

// ---------------- layer-2 gather + fused mean-pool accumulation ----------------
__global__ __launch_bounds__(128) void k_agg2(const int* __restrict__ rec2,
                                              const int* __restrict__ bincur,
                                              const int* __restrict__ nstart,
                                              const int* __restrict__ ncnt,
                                              const float* __restrict__ dinv,
                                              const float* __restrict__ T2,
                                              const int* __restrict__ batch,
                                              float* __restrict__ pool,
                                              float* __restrict__ gcnt) {
  __shared__ int recs[CAP];
  __shared__ float sm[128];
  int k = blockIdx.x, t = threadIdx.x;
  int n0 = k << BSH;
  int cnt = bincur[k];
  for (int i = t; i < cnt; i += 128) recs[i] = rec2[k * CAP + i];
  int node = n0 + (t >> 1);
  int c = t & 1;
  bool nvalid = node < N_NODES;
  float acc = 0.f;
  int r = 0, e = 0;
  if (nvalid) {
    r = nstart[node] - k * CAP;
    e = r + ncnt[node];
    acc = T2[(size_t)node * 2 + c];     // self loop
  }
  __syncthreads();
  for (; r + 1 < e; r += 2) {
    int v0 = recs[r], v1 = recs[r + 1];
    acc += T2[(size_t)(v0 >> BSH) * 2 + c] + T2[(size_t)(v1 >> BSH) * 2 + c];
  }
  if (r < e) acc += T2[(size_t)(recs[r] >> BSH) * 2 + c];
  sm[t] = nvalid ? dinv[node] * acc : 0.f;
  __syncthreads();
  if (t < 64) {                          // wave 0 pools the block's 64 nodes
    int n = n0 + t;
    bool valid = n < N_NODES;
    int b = valid ? batch[n] : -1;
    float vx = sm[2 * t], vy = sm[2 * t + 1];
    int b0 = __shfl(b, 0);
    if (__all(b == b0)) {
      if (b0 >= 0) {
#pragma unroll
        for (int o = 32; o > 0; o >>= 1) {
          vx += __shfl_xor(vx, o);
          vy += __shfl_xor(vy, o);
        }
        if (t == 0) {
          atomicAdd(&pool[b0 * 2 + 0], vx);
          atomicAdd(&pool[b0 * 2 + 1], vy);
          atomicAdd(&gcnt[b0], 64.0f);
        }
      }
    } else if (valid) {
      atomicAdd(&pool[b * 2 + 0], vx);
      atomicAdd(&pool[b * 2 + 1], vy);
      atomicAdd(&gcnt[b], 1.0f);
    }
  }
}

// ---------------- final ----------------
__global__ __launch_bounds__(256) void k_final(const float* __restrict__ pool,
                                               const float* __restrict__ gcnt,
                                               const float* __restrict__ b2,
                                               float* __restrict__ out) {
  int g = threadIdx.x;
  if (g < NGR) {
    float c = fmaxf(gcnt[g], 1.0f);
    float p0 = pool[g * 2 + 0] / c + b2[0];
    float p1 = pool[g * 2 + 1] / c + b2[1];
    float m = fmaxf(p0, p1);
    float l = logf(expf(p0 - m) + expf(p1 - m));
    out[g * 2 + 0] = p0 - m - l;
    out[g * 2 + 1] = p1 - m - l;
  }
}

extern "C" void kernel_launch(void* const* d_in, const int* in_sizes, int n_in,
                              void* d_out, int out_size, void* d_ws, size_t ws_size,
                              hipStream_t stream) {
  const float* x  = (const float*)d_in[0];
  const float* W1 = (const float*)d_in[1];
  const float* b1 = (const float*)d_in[2];
  const float* W2 = (const float*)d_in[3];
  const float* b2 = (const float*)d_in[4];
  const int*   ei = (const int*)d_in[5];
  const int*   bt = (const int*)d_in[6];
  float* out = (float*)d_out;

  char* ws = (char*)d_ws;
  int*   bincur = (int*)ws;    ws += (size_t)NBIN * 4;
  float* pool   = (float*)ws;  ws += 2 * NGR * 4;
  float* gcnt   = (float*)ws;  ws += NGR * 4;       // [bincur..gcnt] one memset
  int*   nstart = (int*)ws;    ws += (size_t)N_NODES * 4;
  int*   ncnt   = (int*)ws;    ws += (size_t)N_NODES * 4;
  float* dinv   = (float*)ws;  ws += (size_t)N_NODES * 4;
  ushort* wt    = (ushort*)ws; ws += (size_t)16 * 512 * 2;
  int*   rec    = (int*)ws;    ws += (size_t)NBIN * CAP * 4;
  int*   rec2   = (int*)ws;    ws += (size_t)NBIN * CAP * 4;
  __half* t1h   = (__half*)ws; ws += (size_t)N_NODES * 16 * 2;
  float* t2     = (float*)ws;  ws += (size_t)N_NODES * 2 * 4;

  hipMemsetAsync(bincur, 0, (size_t)(NBIN + 3 * NGR) * 4, stream);

  k_bin    <<<KBB + 1, 512, 0, stream>>>(ei, bincur, rec, W1, wt);
  k_binsort<<<NBIN, 256, 0, stream>>>(rec, bincur, rec2, nstart, ncnt, dinv);
  k_gemm1  <<<NBIN, 256, 0, stream>>>(x, wt, dinv, t1h);
  k_agg1   <<<NBIN, 256, 0, stream>>>(rec2, bincur, nstart, ncnt, dinv, t1h, b1, W2, t2);
  k_agg2   <<<NBIN, 128, 0, stream>>>(rec2, bincur, nstart, ncnt, dinv, t2, bt, pool, gcnt);
  k_final  <<<1, 256, 0, stream>>>(pool, gcnt, b2, out);
}